// Round 8
// baseline (2299.410 us; speedup 1.0000x reference)
//
#include <hip/hip_runtime.h>

constexpr int N_U  = 100000;
constexpr int N_I  = 100000;
constexpr int NTOT = 200000;   // N_U + N_I
constexpr int D    = 64;
constexpr int Q    = 128;
constexpr int NNZ  = 3200000;
constexpr int SEG  = N_U * D;  // 6,400,000 floats per output segment

constexpr int G1_CHUNK = 400;
constexpr int G1_NBLK  = 250;  // ceil(100000/400)

// bucket sort params: bucket = row >> 9 (512 rows/bucket)
constexpr int BROWS   = 512;
constexpr int NBUCK   = (NTOT + BROWS - 1) / BROWS;  // 391
constexpr int P_CHUNK = 8192;                        // edges per P1/P3 block
constexpr int P_NBLK  = (NNZ + P_CHUNK - 1) / P_CHUNK;  // 391

// G2 tiling: 128 rows x 64 cols per block, K-tiles of 32, double-buffered
constexpr int G2_ROWS = 128;
constexpr int G2_KT   = 32;
constexpr int G2_NBLK = (N_U + G2_ROWS - 1) / G2_ROWS;  // 782

// bf16 helpers (RNE pack, shift unpack)
__device__ __forceinline__ unsigned short f2bf(float f) {
  unsigned int b = __float_as_uint(f);
  return (unsigned short)((b + 0x7fff + ((b >> 16) & 1)) >> 16);
}
__device__ __forceinline__ float bf2f(unsigned short u) {
  return __uint_as_float((unsigned int)u << 16);
}

// ---------------- P1: per-block bucket histogram (LDS only) ----------------
__global__ void __launch_bounds__(512) k_bhist(const int* __restrict__ row,
                                               int* __restrict__ part) {
  __shared__ int h[NBUCK];
  const int t = threadIdx.x;
  if (t < NBUCK) h[t] = 0;
  __syncthreads();
  const int e0 = blockIdx.x * P_CHUNK;
#pragma unroll
  for (int i = 0; i < P_CHUNK / 512; ++i) {
    int e = e0 + i * 512 + t;
    if (e < NNZ) atomicAdd(&h[row[e] >> 9], 1);
  }
  __syncthreads();
  if (t < NBUCK) part[blockIdx.x * NBUCK + t] = h[t];
}

// ---------------- P2: column scan over blocks + bucket scan ----------------
__global__ void __launch_bounds__(512) k_bscan(int* __restrict__ part,
                                               int* __restrict__ outb,
                                               int* __restrict__ bbase) {
  __shared__ int s[512];
  const int t = threadIdx.x;
  int run = 0;
  if (t < NBUCK) {
    for (int blk = 0; blk < P_NBLK; ++blk) {
      int v = part[blk * NBUCK + t];
      outb[blk * NBUCK + t] = run;
      run += v;
    }
  }
  const int own = (t < NBUCK) ? run : 0;
  s[t] = own;
  __syncthreads();
  for (int off = 1; off < 512; off <<= 1) {
    int y = (t >= off) ? s[t - off] : 0;
    __syncthreads();
    s[t] += y;
    __syncthreads();
  }
  int excl = s[t] - own;
  if (t <= NBUCK) bbase[t] = excl;  // bbase[NBUCK] == NNZ
}

// ---------------- P3: scatter edges to bucket-grouped ebuck ----------------
__global__ void __launch_bounds__(512) k_mscat(const int* __restrict__ row,
                                               const int* __restrict__ col,
                                               const float* __restrict__ val,
                                               const int* __restrict__ outb,
                                               const int* __restrict__ bbase,
                                               int2* __restrict__ ebuck) {
  __shared__ int cur[NBUCK];
  const int t = threadIdx.x;
  if (t < NBUCK) cur[t] = bbase[t] + outb[blockIdx.x * NBUCK + t];
  __syncthreads();
  const int e0 = blockIdx.x * P_CHUNK;
#pragma unroll
  for (int i = 0; i < P_CHUNK / 512; ++i) {
    int e = e0 + i * 512 + t;
    if (e < NNZ) {
      int r = row[e];
      int b = r >> 9;
      int pos = atomicAdd(&cur[b], 1);
      ebuck[pos] = make_int2(col[e] | ((r & (BROWS - 1)) << 18), __float_as_int(val[e]));
    }
  }
}

// ---------------- P4: within-bucket row sort + rowptr emission -------------
__global__ void __launch_bounds__(512) k_rsort(const int* __restrict__ bbase,
                                               const int2* __restrict__ ebuck,
                                               int2* __restrict__ edges,
                                               int* __restrict__ rowptr) {
  __shared__ int s[512];
  __shared__ int cur[512];
  const int t = threadIdx.x;
  const int b = blockIdx.x;
  const int eb0 = bbase[b], eb1 = bbase[b + 1];
  cur[t] = 0;
  __syncthreads();
  for (int e = eb0 + t; e < eb1; e += 512) atomicAdd(&cur[ebuck[e].x >> 18], 1);
  __syncthreads();
  const int own = cur[t];
  s[t] = own;
  __syncthreads();
  for (int off = 1; off < 512; off <<= 1) {
    int y = (t >= off) ? s[t - off] : 0;
    __syncthreads();
    s[t] += y;
    __syncthreads();
  }
  const int excl = s[t] - own;
  const int r = (b << 9) + t;
  if (r < NTOT) rowptr[r] = eb0 + excl;
  if (b == NBUCK - 1 && t == 0) rowptr[NTOT] = NNZ;
  cur[t] = eb0 + excl;
  __syncthreads();
  for (int e = eb0 + t; e < eb1; e += 512) {
    int2 kv = ebuck[e];
    int pos = atomicAdd(&cur[kv.x >> 18], 1);
    edges[pos] = make_int2(kv.x & 0x3FFFF, kv.y);
  }
}

// ---------------- cvt: concat inputs -> bf16 ego buffer --------------------
__global__ void k_cvt(const float* __restrict__ user_emb,
                      const float* __restrict__ item_emb,
                      unsigned short* __restrict__ e0) {
  int i = blockIdx.x * 256 + threadIdx.x;  // 8 elems per thread
  if (i >= NTOT * D / 8) return;
  size_t base = (size_t)i * 8;
  const float* src = (base < (size_t)SEG) ? (user_emb + base) : (item_emb + base - SEG);
  float4 v0 = *reinterpret_cast<const float4*>(src);
  float4 v1 = *reinterpret_cast<const float4*>(src + 4);
  union { unsigned short us[8]; uint4 u4; } pk;
  pk.us[0] = f2bf(v0.x); pk.us[1] = f2bf(v0.y); pk.us[2] = f2bf(v0.z); pk.us[3] = f2bf(v0.w);
  pk.us[4] = f2bf(v1.x); pk.us[5] = f2bf(v1.y); pk.us[6] = f2bf(v1.z); pk.us[7] = f2bf(v1.w);
  *reinterpret_cast<uint4*>(e0 + base) = pk.u4;
}

// ---------------- SpMM bf16 (gather, wave per row, lane = d, 8-deep MLP) ----
__global__ void k_spmm(const int* __restrict__ rowptr, const int2* __restrict__ edges,
                       const unsigned short* __restrict__ src,
                       unsigned short* __restrict__ dst) {
  const int r = (blockIdx.x * 256 + threadIdx.x) >> 6;
  const int lane = threadIdx.x & 63;
  if (r >= NTOT) return;
  const int e0 = rowptr[r], e1 = rowptr[r + 1];
  float sum = 0.f;
  int e = e0;
  for (; e + 8 <= e1; e += 8) {
    int2 d0 = edges[e + 0], d1 = edges[e + 1], d2 = edges[e + 2], d3 = edges[e + 3];
    int2 d4 = edges[e + 4], d5 = edges[e + 5], d6 = edges[e + 6], d7 = edges[e + 7];
    unsigned short u0 = src[((size_t)d0.x << 6) + lane];
    unsigned short u1 = src[((size_t)d1.x << 6) + lane];
    unsigned short u2 = src[((size_t)d2.x << 6) + lane];
    unsigned short u3 = src[((size_t)d3.x << 6) + lane];
    unsigned short u4 = src[((size_t)d4.x << 6) + lane];
    unsigned short u5 = src[((size_t)d5.x << 6) + lane];
    unsigned short u6 = src[((size_t)d6.x << 6) + lane];
    unsigned short u7 = src[((size_t)d7.x << 6) + lane];
    sum = fmaf(__int_as_float(d0.y), bf2f(u0), sum);
    sum = fmaf(__int_as_float(d1.y), bf2f(u1), sum);
    sum = fmaf(__int_as_float(d2.y), bf2f(u2), sum);
    sum = fmaf(__int_as_float(d3.y), bf2f(u3), sum);
    sum = fmaf(__int_as_float(d4.y), bf2f(u4), sum);
    sum = fmaf(__int_as_float(d5.y), bf2f(u5), sum);
    sum = fmaf(__int_as_float(d6.y), bf2f(u6), sum);
    sum = fmaf(__int_as_float(d7.y), bf2f(u7), sum);
  }
  for (; e + 2 <= e1; e += 2) {
    int2 d0 = edges[e + 0], d1 = edges[e + 1];
    unsigned short u0 = src[((size_t)d0.x << 6) + lane];
    unsigned short u1 = src[((size_t)d1.x << 6) + lane];
    sum = fmaf(__int_as_float(d0.y), bf2f(u0), sum);
    sum = fmaf(__int_as_float(d1.y), bf2f(u1), sum);
  }
  if (e < e1) {
    int2 d0 = edges[e];
    sum = fmaf(__int_as_float(d0.y), bf2f(src[((size_t)d0.x << 6) + lane]), sum);
  }
  dst[((size_t)r << 6) + lane] = f2bf(sum);
}

// ---------------- mean: (e1+e2+e3)/3 -> f32 out segments -------------------
__global__ void k_mean(const unsigned short* __restrict__ e1,
                       const unsigned short* __restrict__ e2,
                       const unsigned short* __restrict__ e3,
                       float* __restrict__ mean_u, float* __restrict__ mean_i) {
  int i = blockIdx.x * 256 + threadIdx.x;  // 8 elems per thread
  if (i >= NTOT * D / 8) return;
  size_t base = (size_t)i * 8;
  uint4 a = *reinterpret_cast<const uint4*>(e1 + base);
  uint4 b = *reinterpret_cast<const uint4*>(e2 + base);
  uint4 c = *reinterpret_cast<const uint4*>(e3 + base);
  union { uint4 u4; unsigned short us[8]; } ua, ub, uc;
  ua.u4 = a; ub.u4 = b; uc.u4 = c;
  float o[8];
#pragma unroll
  for (int j = 0; j < 8; ++j)
    o[j] = (bf2f(ua.us[j]) + bf2f(ub.us[j]) + bf2f(uc.us[j])) * (1.f / 3.f);
  float* dstp = (base < (size_t)SEG) ? (mean_u + base) : (mean_i + base - SEG);
  *reinterpret_cast<float4*>(dstp) = make_float4(o[0], o[1], o[2], o[3]);
  *reinterpret_cast<float4*>(dstp + 4) = make_float4(o[4], o[5], o[6], o[7]);
}

// ---------------- G1: Ppart[mat][blk] = W(128 x nchunk) @ X(nchunk x 64) ----
__global__ void __launch_bounds__(512) k_g1(const float* __restrict__ ut,
                                            const float* __restrict__ vt,
                                            const float* __restrict__ accu,
                                            const float* __restrict__ acci,
                                            float* __restrict__ Ppart) {
  __shared__ float Wl[128 * 65];
  __shared__ float Xl[64 * 64];
  const int mat = blockIdx.y;
  const float* __restrict__ W = mat ? vt : ut;      // (Q, N_U) row-major
  const float* __restrict__ X = mat ? acci : accu;  // (N_U, 64) holds mean
  const int t = threadIdx.x;
  const int q0 = (t >> 4) * 4;   // 32 q-groups
  const int d0 = (t & 15) * 4;   // 16 d-groups
  const int n0 = blockIdx.x * G1_CHUNK;
  const int n1 = min(n0 + G1_CHUNK, N_U);
  float4 a0 = {0, 0, 0, 0}, a1 = {0, 0, 0, 0}, a2 = {0, 0, 0, 0}, a3 = {0, 0, 0, 0};
  for (int k = n0; k < n1; k += 64) {
#pragma unroll
    for (int rep = 0; rep < 2; ++rep) {
      int f4 = t + rep * 512;
      int row = f4 >> 4;
      int c4 = (f4 & 15) * 4;
      int gr = k + row;
      float4 v = (gr < n1) ? *reinterpret_cast<const float4*>(X + (size_t)gr * 64 + c4)
                           : float4{0, 0, 0, 0};
      *reinterpret_cast<float4*>(&Xl[row * 64 + c4]) = v;
    }
    {
      int q = t >> 2;
      int c16 = (t & 3) * 16;
#pragma unroll
      for (int jj = 0; jj < 4; ++jj) {
        int kk = c16 + jj * 4;
        int gk = k + kk;
        float4 v = (gk < n1) ? *reinterpret_cast<const float4*>(W + (size_t)q * N_U + gk)
                             : float4{0, 0, 0, 0};
        *reinterpret_cast<float4*>(&Wl[q * 65 + kk]) = v;
      }
    }
    __syncthreads();
#pragma unroll 2
    for (int kk = 0; kk < 64; kk += 4) {
      float4 w0 = *reinterpret_cast<const float4*>(&Wl[(q0 + 0) * 65 + kk]);
      float4 w1 = *reinterpret_cast<const float4*>(&Wl[(q0 + 1) * 65 + kk]);
      float4 w2 = *reinterpret_cast<const float4*>(&Wl[(q0 + 2) * 65 + kk]);
      float4 w3 = *reinterpret_cast<const float4*>(&Wl[(q0 + 3) * 65 + kk]);
      float4 x0 = *reinterpret_cast<const float4*>(&Xl[(kk + 0) * 64 + d0]);
      float4 x1 = *reinterpret_cast<const float4*>(&Xl[(kk + 1) * 64 + d0]);
      float4 x2 = *reinterpret_cast<const float4*>(&Xl[(kk + 2) * 64 + d0]);
      float4 x3 = *reinterpret_cast<const float4*>(&Xl[(kk + 3) * 64 + d0]);
#define FMA16(aj, wj)                                                                 \
  aj.x = fmaf(wj.x, x0.x, aj.x); aj.y = fmaf(wj.x, x0.y, aj.y);                       \
  aj.z = fmaf(wj.x, x0.z, aj.z); aj.w = fmaf(wj.x, x0.w, aj.w);                       \
  aj.x = fmaf(wj.y, x1.x, aj.x); aj.y = fmaf(wj.y, x1.y, aj.y);                       \
  aj.z = fmaf(wj.y, x1.z, aj.z); aj.w = fmaf(wj.y, x1.w, aj.w);                       \
  aj.x = fmaf(wj.z, x2.x, aj.x); aj.y = fmaf(wj.z, x2.y, aj.y);                       \
  aj.z = fmaf(wj.z, x2.z, aj.z); aj.w = fmaf(wj.z, x2.w, aj.w);                       \
  aj.x = fmaf(wj.w, x3.x, aj.x); aj.y = fmaf(wj.w, x3.y, aj.y);                       \
  aj.z = fmaf(wj.w, x3.z, aj.z); aj.w = fmaf(wj.w, x3.w, aj.w);
      FMA16(a0, w0)
      FMA16(a1, w1)
      FMA16(a2, w2)
      FMA16(a3, w3)
#undef FMA16
    }
    __syncthreads();
  }
  float* dst = Ppart + ((size_t)mat * G1_NBLK + blockIdx.x) * (Q * D);
  *reinterpret_cast<float4*>(dst + (q0 + 0) * 64 + d0) = a0;
  *reinterpret_cast<float4*>(dst + (q0 + 1) * 64 + d0) = a1;
  *reinterpret_cast<float4*>(dst + (q0 + 2) * 64 + d0) = a2;
  *reinterpret_cast<float4*>(dst + (q0 + 3) * 64 + d0) = a3;
}

// P[mat][q][d] = 3 * sum_blk Ppart[mat][blk][q][d]
__global__ void k_reduce(const float* __restrict__ Ppart, float* __restrict__ P) {
  int idx = blockIdx.x * 256 + threadIdx.x;  // 0..16383
  if (idx >= 2 * Q * D) return;
  int mat = idx >> 13;
  int qd = idx & (Q * D - 1);
  const float* src = Ppart + (size_t)mat * G1_NBLK * (Q * D) + qd;
  float s = 0.f;
#pragma unroll 4
  for (int b = 0; b < G1_NBLK; ++b) s += src[(size_t)b * (Q * D)];
  P[idx] = s * 3.f;
}

// ---------------- G2: K-tiled dbuf GEMM, out(N x 64) = M(N x 128) @ P(128 x 64)
// Block 256 thr: 128 rows x 64 cols. K-tiles of 32, double-buffered LDS
// (M tile 2x128x32 f32 as swizzled float4 = 32 KB; P tile 2x32x64 = 16 KB).
// Thread = 8 rows x 4 cols (32 acc), 12 ds_read_b128 per 128 FMA.
__global__ void __launch_bounds__(256) k_g2(const float* __restrict__ u_mul_s,
                                            const float* __restrict__ v_mul_s,
                                            const float* __restrict__ P,
                                            float* __restrict__ svd_u,
                                            float* __restrict__ svd_i) {
  __shared__ float4 Ml4[2][G2_ROWS][8];   // [buf][row][kf4 swizzled]
  __shared__ float  Pl[2][G2_KT][64];     // [buf][k][c]
  const int mat = blockIdx.y;
  const float* __restrict__ M  = mat ? v_mul_s : u_mul_s;  // (N_U, 128)
  const float* __restrict__ Pg = mat ? P : (P + Q * D);
  float* __restrict__ outp     = mat ? svd_i : svd_u;
  const int t = threadIdx.x;
  const int r0 = blockIdx.x * G2_ROWS;

  auto stage = [&](int kt, int buf) {
    // M tile: 1024 float4, coalesced (8 threads span one row's 128 B k-tile)
#pragma unroll
    for (int i = 0; i < 4; ++i) {
      int f4 = i * 256 + t;
      int row = f4 >> 3;
      int kf4 = f4 & 7;
      int gr = r0 + row;
      float4 v = {0, 0, 0, 0};
      if (gr < N_U)
        v = *reinterpret_cast<const float4*>(M + (size_t)gr * Q + kt * G2_KT + kf4 * 4);
      Ml4[buf][row][kf4 ^ ((row >> 3) & 7)] = v;
    }
    // P tile: 512 float4
#pragma unroll
    for (int i = 0; i < 2; ++i) {
      int f4 = i * 256 + t;
      int k = f4 >> 4;
      int c4 = (f4 & 15) * 4;
      *reinterpret_cast<float4*>(&Pl[buf][k][c4]) =
          *reinterpret_cast<const float4*>(Pg + (size_t)(kt * G2_KT + k) * 64 + c4);
    }
  };

  const int cg = t & 15;        // col group
  const int rg = t >> 4;        // row group
  const int c0 = cg * 4;
  const int rb = rg * 8;
  const int swz = rg & 7;       // (row>>3)&7 is constant (=rg) for this thread's rows

  float4 a[8];
#pragma unroll
  for (int rr = 0; rr < 8; ++rr) a[rr] = float4{0, 0, 0, 0};

  stage(0, 0);
  __syncthreads();
#pragma unroll
  for (int kt = 0; kt < 4; ++kt) {
    const int buf = kt & 1;
    if (kt < 3) stage(kt + 1, buf ^ 1);  // issue next-tile loads before compute
#pragma unroll
    for (int kk = 0; kk < G2_KT; kk += 4) {
      float4 p0 = *reinterpret_cast<const float4*>(&Pl[buf][kk + 0][c0]);
      float4 p1 = *reinterpret_cast<const float4*>(&Pl[buf][kk + 1][c0]);
      float4 p2 = *reinterpret_cast<const float4*>(&Pl[buf][kk + 2][c0]);
      float4 p3 = *reinterpret_cast<const float4*>(&Pl[buf][kk + 3][c0]);
      const int ks = (kk >> 2) ^ swz;
#define G2ROW(rr)                                                                     \
  {                                                                                   \
    float4 m = Ml4[buf][rb + rr][ks];                                                 \
    a[rr].x = fmaf(m.x, p0.x, a[rr].x); a[rr].y = fmaf(m.x, p0.y, a[rr].y);           \
    a[rr].z = fmaf(m.x, p0.z, a[rr].z); a[rr].w = fmaf(m.x, p0.w, a[rr].w);           \
    a[rr].x = fmaf(m.y, p1.x, a[rr].x); a[rr].y = fmaf(m.y, p1.y, a[rr].y);           \
    a[rr].z = fmaf(m.y, p1.z, a[rr].z); a[rr].w = fmaf(m.y, p1.w, a[rr].w);           \
    a[rr].x = fmaf(m.z, p2.x, a[rr].x); a[rr].y = fmaf(m.z, p2.y, a[rr].y);           \
    a[rr].z = fmaf(m.z, p2.z, a[rr].z); a[rr].w = fmaf(m.z, p2.w, a[rr].w);           \
    a[rr].x = fmaf(m.w, p3.x, a[rr].x); a[rr].y = fmaf(m.w, p3.y, a[rr].y);           \
    a[rr].z = fmaf(m.w, p3.z, a[rr].z); a[rr].w = fmaf(m.w, p3.w, a[rr].w);           \
  }
      G2ROW(0) G2ROW(1) G2ROW(2) G2ROW(3) G2ROW(4) G2ROW(5) G2ROW(6) G2ROW(7)
#undef G2ROW
    }
    __syncthreads();
  }
#pragma unroll
  for (int rr = 0; rr < 8; ++rr) {
    int gr = r0 + rb + rr;
    if (gr < N_U)
      *reinterpret_cast<float4*>(outp + (size_t)gr * D + c0) = a[rr];
  }
}

extern "C" void kernel_launch(void* const* d_in, const int* in_sizes, int n_in,
                              void* d_out, int out_size, void* d_ws, size_t ws_size,
                              hipStream_t stream) {
  const float* user_emb = (const float*)d_in[0];
  const float* item_emb = (const float*)d_in[1];
  const int*   adj_row  = (const int*)d_in[2];
  const int*   adj_col  = (const int*)d_in[3];
  const float* adj_vals = (const float*)d_in[4];
  const float* ut       = (const float*)d_in[5];
  const float* vt       = (const float*)d_in[6];
  const float* u_mul_s  = (const float*)d_in[7];
  const float* v_mul_s  = (const float*)d_in[8];
  float* out = (float*)d_out;

  char* ws = (char*)d_ws;
  size_t off = 0;
  auto alloc = [&](size_t bytes) -> void* {
    void* p = ws + off;
    off = (off + bytes + 255) & ~(size_t)255;
    return p;
  };
  unsigned short* eb0 = (unsigned short*)alloc((size_t)NTOT * D * 2);  // 25.6 MB
  unsigned short* eb1 = (unsigned short*)alloc((size_t)NTOT * D * 2);
  unsigned short* eb2 = (unsigned short*)alloc((size_t)NTOT * D * 2);
  unsigned short* eb3 = (unsigned short*)alloc((size_t)NTOT * D * 2);
  int2*  ebuck  = (int2*)alloc((size_t)NNZ * 8);                  // 25.6 MB
  int2*  edges  = (int2*)alloc((size_t)NNZ * 8);                  // 25.6 MB
  int*   rowptr = (int*)alloc((size_t)(NTOT + 1) * 4);
  int*   part   = (int*)alloc((size_t)P_NBLK * NBUCK * 4);        // 611 KB
  int*   outb   = (int*)alloc((size_t)P_NBLK * NBUCK * 4);        // 611 KB
  int*   bbase  = (int*)alloc((size_t)(NBUCK + 1) * 4);
  float* P      = (float*)alloc(2 * Q * D * 4);                   // 64 KB
  float* Ppart  = (float*)alloc((size_t)2 * G1_NBLK * Q * D * 4); // 16.4 MB

  float* mean_u = out;                   // seg0
  float* svd_u  = out + (size_t)SEG;     // seg1
  float* mean_i = out + 2 * (size_t)SEG; // seg2
  float* svd_i  = out + 3 * (size_t)SEG; // seg3

  // CSR build: atomic-free multisplit (bucket = row>>9)
  k_bhist<<<P_NBLK, 512, 0, stream>>>(adj_row, part);
  k_bscan<<<1, 512, 0, stream>>>(part, outb, bbase);
  k_mscat<<<P_NBLK, 512, 0, stream>>>(adj_row, adj_col, adj_vals, outb, bbase, ebuck);
  k_rsort<<<NBUCK, 512, 0, stream>>>(bbase, ebuck, edges, rowptr);

  // inputs -> bf16 concat ego
  k_cvt<<<(NTOT * D / 8 + 255) / 256, 256, 0, stream>>>(user_emb, item_emb, eb0);

  const int spmmGrid = (NTOT * 64) / 256;
  k_spmm<<<spmmGrid, 256, 0, stream>>>(rowptr, edges, eb0, eb1);
  k_spmm<<<spmmGrid, 256, 0, stream>>>(rowptr, edges, eb1, eb2);
  k_spmm<<<spmmGrid, 256, 0, stream>>>(rowptr, edges, eb2, eb3);

  // mean = (e1+e2+e3)/3 -> f32 segments
  k_mean<<<(NTOT * D / 8 + 255) / 256, 256, 0, stream>>>(eb1, eb2, eb3, mean_u, mean_i);

  // P_u partials (y=0, from mean_u/ut), P_v partials (y=1, from mean_i/vt)
  k_g1<<<dim3(G1_NBLK, 2), 512, 0, stream>>>(ut, vt, mean_u, mean_i, Ppart);
  k_reduce<<<(2 * Q * D + 255) / 256, 256, 0, stream>>>(Ppart, P);

  // y=0: svd_u = u_mul_s @ P_v ; y=1: svd_i = v_mul_s @ P_u
  k_g2<<<dim3(G2_NBLK, 2), 256, 0, stream>>>(u_mul_s, v_mul_s, P, svd_u, svd_i);
}

// Round 9
// 660.466 us; speedup vs baseline: 3.4815x; 3.4815x over previous
//
#include <hip/hip_runtime.h>

constexpr int N_U  = 100000;
constexpr int N_I  = 100000;
constexpr int NTOT = 200000;   // N_U + N_I
constexpr int D    = 64;
constexpr int Q    = 128;
constexpr int NNZ  = 3200000;
constexpr int SEG  = N_U * D;  // 6,400,000 floats per output segment

constexpr int G1_CHUNK = 400;
constexpr int G1_NBLK  = 250;  // ceil(100000/400)

// bucket sort params: bucket = row >> 9 (512 rows/bucket)
constexpr int BROWS   = 512;
constexpr int NBUCK   = (NTOT + BROWS - 1) / BROWS;  // 391
constexpr int P_CHUNK = 8192;                        // edges per P1/P3 block
constexpr int P_NBLK  = (NNZ + P_CHUNK - 1) / P_CHUNK;  // 391

// G2: 64 rows x 64 cols per block; P in LDS (32 KB), M streamed from global
constexpr int G2_ROWS = 64;
constexpr int G2_NBLK = (N_U + G2_ROWS - 1) / G2_ROWS;  // 1563

// bf16 helpers (RNE pack, shift unpack)
__device__ __forceinline__ unsigned short f2bf(float f) {
  unsigned int b = __float_as_uint(f);
  return (unsigned short)((b + 0x7fff + ((b >> 16) & 1)) >> 16);
}
__device__ __forceinline__ float bf2f(unsigned short u) {
  return __uint_as_float((unsigned int)u << 16);
}

// ---------------- P1: per-block bucket histogram (LDS only) ----------------
__global__ void __launch_bounds__(512) k_bhist(const int* __restrict__ row,
                                               int* __restrict__ part) {
  __shared__ int h[NBUCK];
  const int t = threadIdx.x;
  if (t < NBUCK) h[t] = 0;
  __syncthreads();
  const int e0 = blockIdx.x * P_CHUNK;
#pragma unroll
  for (int i = 0; i < P_CHUNK / 512; ++i) {
    int e = e0 + i * 512 + t;
    if (e < NNZ) atomicAdd(&h[row[e] >> 9], 1);
  }
  __syncthreads();
  if (t < NBUCK) part[blockIdx.x * NBUCK + t] = h[t];
}

// ---------------- P2: column scan over blocks + bucket scan ----------------
__global__ void __launch_bounds__(512) k_bscan(int* __restrict__ part,
                                               int* __restrict__ outb,
                                               int* __restrict__ bbase) {
  __shared__ int s[512];
  const int t = threadIdx.x;
  int run = 0;
  if (t < NBUCK) {
    for (int blk = 0; blk < P_NBLK; ++blk) {
      int v = part[blk * NBUCK + t];
      outb[blk * NBUCK + t] = run;
      run += v;
    }
  }
  const int own = (t < NBUCK) ? run : 0;
  s[t] = own;
  __syncthreads();
  for (int off = 1; off < 512; off <<= 1) {
    int y = (t >= off) ? s[t - off] : 0;
    __syncthreads();
    s[t] += y;
    __syncthreads();
  }
  int excl = s[t] - own;
  if (t <= NBUCK) bbase[t] = excl;  // bbase[NBUCK] == NNZ
}

// ---------------- P3: scatter edges to bucket-grouped ebuck ----------------
__global__ void __launch_bounds__(512) k_mscat(const int* __restrict__ row,
                                               const int* __restrict__ col,
                                               const float* __restrict__ val,
                                               const int* __restrict__ outb,
                                               const int* __restrict__ bbase,
                                               int2* __restrict__ ebuck) {
  __shared__ int cur[NBUCK];
  const int t = threadIdx.x;
  if (t < NBUCK) cur[t] = bbase[t] + outb[blockIdx.x * NBUCK + t];
  __syncthreads();
  const int e0 = blockIdx.x * P_CHUNK;
#pragma unroll
  for (int i = 0; i < P_CHUNK / 512; ++i) {
    int e = e0 + i * 512 + t;
    if (e < NNZ) {
      int r = row[e];
      int b = r >> 9;
      int pos = atomicAdd(&cur[b], 1);
      ebuck[pos] = make_int2(col[e] | ((r & (BROWS - 1)) << 18), __float_as_int(val[e]));
    }
  }
}

// ---------------- P4: within-bucket row sort + rowptr emission -------------
__global__ void __launch_bounds__(512) k_rsort(const int* __restrict__ bbase,
                                               const int2* __restrict__ ebuck,
                                               int2* __restrict__ edges,
                                               int* __restrict__ rowptr) {
  __shared__ int s[512];
  __shared__ int cur[512];
  const int t = threadIdx.x;
  const int b = blockIdx.x;
  const int eb0 = bbase[b], eb1 = bbase[b + 1];
  cur[t] = 0;
  __syncthreads();
  for (int e = eb0 + t; e < eb1; e += 512) atomicAdd(&cur[ebuck[e].x >> 18], 1);
  __syncthreads();
  const int own = cur[t];
  s[t] = own;
  __syncthreads();
  for (int off = 1; off < 512; off <<= 1) {
    int y = (t >= off) ? s[t - off] : 0;
    __syncthreads();
    s[t] += y;
    __syncthreads();
  }
  const int excl = s[t] - own;
  const int r = (b << 9) + t;
  if (r < NTOT) rowptr[r] = eb0 + excl;
  if (b == NBUCK - 1 && t == 0) rowptr[NTOT] = NNZ;
  cur[t] = eb0 + excl;
  __syncthreads();
  for (int e = eb0 + t; e < eb1; e += 512) {
    int2 kv = ebuck[e];
    int pos = atomicAdd(&cur[kv.x >> 18], 1);
    edges[pos] = make_int2(kv.x & 0x3FFFF, kv.y);
  }
}

// ---------------- cvt: concat inputs -> bf16 ego buffer --------------------
__global__ void k_cvt(const float* __restrict__ user_emb,
                      const float* __restrict__ item_emb,
                      unsigned short* __restrict__ e0) {
  int i = blockIdx.x * 256 + threadIdx.x;  // 8 elems per thread
  if (i >= NTOT * D / 8) return;
  size_t base = (size_t)i * 8;
  const float* src = (base < (size_t)SEG) ? (user_emb + base) : (item_emb + base - SEG);
  float4 v0 = *reinterpret_cast<const float4*>(src);
  float4 v1 = *reinterpret_cast<const float4*>(src + 4);
  union { unsigned short us[8]; uint4 u4; } pk;
  pk.us[0] = f2bf(v0.x); pk.us[1] = f2bf(v0.y); pk.us[2] = f2bf(v0.z); pk.us[3] = f2bf(v0.w);
  pk.us[4] = f2bf(v1.x); pk.us[5] = f2bf(v1.y); pk.us[6] = f2bf(v1.z); pk.us[7] = f2bf(v1.w);
  *reinterpret_cast<uint4*>(e0 + base) = pk.u4;
}

// ---------------- SpMM bf16 (gather, wave per row, lane = d, 8-deep MLP) ----
__global__ void k_spmm(const int* __restrict__ rowptr, const int2* __restrict__ edges,
                       const unsigned short* __restrict__ src,
                       unsigned short* __restrict__ dst) {
  const int r = (blockIdx.x * 256 + threadIdx.x) >> 6;
  const int lane = threadIdx.x & 63;
  if (r >= NTOT) return;
  const int e0 = rowptr[r], e1 = rowptr[r + 1];
  float sum = 0.f;
  int e = e0;
  for (; e + 8 <= e1; e += 8) {
    int2 d0 = edges[e + 0], d1 = edges[e + 1], d2 = edges[e + 2], d3 = edges[e + 3];
    int2 d4 = edges[e + 4], d5 = edges[e + 5], d6 = edges[e + 6], d7 = edges[e + 7];
    unsigned short u0 = src[((size_t)d0.x << 6) + lane];
    unsigned short u1 = src[((size_t)d1.x << 6) + lane];
    unsigned short u2 = src[((size_t)d2.x << 6) + lane];
    unsigned short u3 = src[((size_t)d3.x << 6) + lane];
    unsigned short u4 = src[((size_t)d4.x << 6) + lane];
    unsigned short u5 = src[((size_t)d5.x << 6) + lane];
    unsigned short u6 = src[((size_t)d6.x << 6) + lane];
    unsigned short u7 = src[((size_t)d7.x << 6) + lane];
    sum = fmaf(__int_as_float(d0.y), bf2f(u0), sum);
    sum = fmaf(__int_as_float(d1.y), bf2f(u1), sum);
    sum = fmaf(__int_as_float(d2.y), bf2f(u2), sum);
    sum = fmaf(__int_as_float(d3.y), bf2f(u3), sum);
    sum = fmaf(__int_as_float(d4.y), bf2f(u4), sum);
    sum = fmaf(__int_as_float(d5.y), bf2f(u5), sum);
    sum = fmaf(__int_as_float(d6.y), bf2f(u6), sum);
    sum = fmaf(__int_as_float(d7.y), bf2f(u7), sum);
  }
  for (; e + 2 <= e1; e += 2) {
    int2 d0 = edges[e + 0], d1 = edges[e + 1];
    unsigned short u0 = src[((size_t)d0.x << 6) + lane];
    unsigned short u1 = src[((size_t)d1.x << 6) + lane];
    sum = fmaf(__int_as_float(d0.y), bf2f(u0), sum);
    sum = fmaf(__int_as_float(d1.y), bf2f(u1), sum);
  }
  if (e < e1) {
    int2 d0 = edges[e];
    sum = fmaf(__int_as_float(d0.y), bf2f(src[((size_t)d0.x << 6) + lane]), sum);
  }
  dst[((size_t)r << 6) + lane] = f2bf(sum);
}

// ---------------- mean: (e1+e2+e3)/3 -> f32 out segments -------------------
__global__ void k_mean(const unsigned short* __restrict__ e1,
                       const unsigned short* __restrict__ e2,
                       const unsigned short* __restrict__ e3,
                       float* __restrict__ mean_u, float* __restrict__ mean_i) {
  int i = blockIdx.x * 256 + threadIdx.x;  // 8 elems per thread
  if (i >= NTOT * D / 8) return;
  size_t base = (size_t)i * 8;
  uint4 a = *reinterpret_cast<const uint4*>(e1 + base);
  uint4 b = *reinterpret_cast<const uint4*>(e2 + base);
  uint4 c = *reinterpret_cast<const uint4*>(e3 + base);
  union { uint4 u4; unsigned short us[8]; } ua, ub, uc;
  ua.u4 = a; ub.u4 = b; uc.u4 = c;
  float o[8];
#pragma unroll
  for (int j = 0; j < 8; ++j)
    o[j] = (bf2f(ua.us[j]) + bf2f(ub.us[j]) + bf2f(uc.us[j])) * (1.f / 3.f);
  float* dstp = (base < (size_t)SEG) ? (mean_u + base) : (mean_i + base - SEG);
  *reinterpret_cast<float4*>(dstp) = make_float4(o[0], o[1], o[2], o[3]);
  *reinterpret_cast<float4*>(dstp + 4) = make_float4(o[4], o[5], o[6], o[7]);
}

// ---------------- G1: Ppart[mat][blk] = W(128 x nchunk) @ X(nchunk x 64) ----
__global__ void __launch_bounds__(512) k_g1(const float* __restrict__ ut,
                                            const float* __restrict__ vt,
                                            const float* __restrict__ accu,
                                            const float* __restrict__ acci,
                                            float* __restrict__ Ppart) {
  __shared__ float Wl[128 * 65];
  __shared__ float Xl[64 * 64];
  const int mat = blockIdx.y;
  const float* __restrict__ W = mat ? vt : ut;      // (Q, N_U) row-major
  const float* __restrict__ X = mat ? acci : accu;  // (N_U, 64) holds mean
  const int t = threadIdx.x;
  const int q0 = (t >> 4) * 4;   // 32 q-groups
  const int d0 = (t & 15) * 4;   // 16 d-groups
  const int n0 = blockIdx.x * G1_CHUNK;
  const int n1 = min(n0 + G1_CHUNK, N_U);
  float4 a0 = {0, 0, 0, 0}, a1 = {0, 0, 0, 0}, a2 = {0, 0, 0, 0}, a3 = {0, 0, 0, 0};
  for (int k = n0; k < n1; k += 64) {
#pragma unroll
    for (int rep = 0; rep < 2; ++rep) {
      int f4 = t + rep * 512;
      int row = f4 >> 4;
      int c4 = (f4 & 15) * 4;
      int gr = k + row;
      float4 v = (gr < n1) ? *reinterpret_cast<const float4*>(X + (size_t)gr * 64 + c4)
                           : float4{0, 0, 0, 0};
      *reinterpret_cast<float4*>(&Xl[row * 64 + c4]) = v;
    }
    {
      int q = t >> 2;
      int c16 = (t & 3) * 16;
#pragma unroll
      for (int jj = 0; jj < 4; ++jj) {
        int kk = c16 + jj * 4;
        int gk = k + kk;
        float4 v = (gk < n1) ? *reinterpret_cast<const float4*>(W + (size_t)q * N_U + gk)
                             : float4{0, 0, 0, 0};
        *reinterpret_cast<float4*>(&Wl[q * 65 + kk]) = v;
      }
    }
    __syncthreads();
#pragma unroll 2
    for (int kk = 0; kk < 64; kk += 4) {
      float4 w0 = *reinterpret_cast<const float4*>(&Wl[(q0 + 0) * 65 + kk]);
      float4 w1 = *reinterpret_cast<const float4*>(&Wl[(q0 + 1) * 65 + kk]);
      float4 w2 = *reinterpret_cast<const float4*>(&Wl[(q0 + 2) * 65 + kk]);
      float4 w3 = *reinterpret_cast<const float4*>(&Wl[(q0 + 3) * 65 + kk]);
      float4 x0 = *reinterpret_cast<const float4*>(&Xl[(kk + 0) * 64 + d0]);
      float4 x1 = *reinterpret_cast<const float4*>(&Xl[(kk + 1) * 64 + d0]);
      float4 x2 = *reinterpret_cast<const float4*>(&Xl[(kk + 2) * 64 + d0]);
      float4 x3 = *reinterpret_cast<const float4*>(&Xl[(kk + 3) * 64 + d0]);
#define FMA16(aj, wj)                                                                 \
  aj.x = fmaf(wj.x, x0.x, aj.x); aj.y = fmaf(wj.x, x0.y, aj.y);                       \
  aj.z = fmaf(wj.x, x0.z, aj.z); aj.w = fmaf(wj.x, x0.w, aj.w);                       \
  aj.x = fmaf(wj.y, x1.x, aj.x); aj.y = fmaf(wj.y, x1.y, aj.y);                       \
  aj.z = fmaf(wj.y, x1.z, aj.z); aj.w = fmaf(wj.y, x1.w, aj.w);                       \
  aj.x = fmaf(wj.z, x2.x, aj.x); aj.y = fmaf(wj.z, x2.y, aj.y);                       \
  aj.z = fmaf(wj.z, x2.z, aj.z); aj.w = fmaf(wj.z, x2.w, aj.w);                       \
  aj.x = fmaf(wj.w, x3.x, aj.x); aj.y = fmaf(wj.w, x3.y, aj.y);                       \
  aj.z = fmaf(wj.w, x3.z, aj.z); aj.w = fmaf(wj.w, x3.w, aj.w);
      FMA16(a0, w0)
      FMA16(a1, w1)
      FMA16(a2, w2)
      FMA16(a3, w3)
#undef FMA16
    }
    __syncthreads();
  }
  float* dst = Ppart + ((size_t)mat * G1_NBLK + blockIdx.x) * (Q * D);
  *reinterpret_cast<float4*>(dst + (q0 + 0) * 64 + d0) = a0;
  *reinterpret_cast<float4*>(dst + (q0 + 1) * 64 + d0) = a1;
  *reinterpret_cast<float4*>(dst + (q0 + 2) * 64 + d0) = a2;
  *reinterpret_cast<float4*>(dst + (q0 + 3) * 64 + d0) = a3;
}

// P[mat][q][d] = 3 * sum_blk Ppart[mat][blk][q][d]
__global__ void k_reduce(const float* __restrict__ Ppart, float* __restrict__ P) {
  int idx = blockIdx.x * 256 + threadIdx.x;  // 0..16383
  if (idx >= 2 * Q * D) return;
  int mat = idx >> 13;
  int qd = idx & (Q * D - 1);
  const float* src = Ppart + (size_t)mat * G1_NBLK * (Q * D) + qd;
  float s = 0.f;
#pragma unroll 4
  for (int b = 0; b < G1_NBLK; ++b) s += src[(size_t)b * (Q * D)];
  P[idx] = s * 3.f;
}

// ---------------- G2: out(N x 64) = M(N x 128) @ P(128 x 64) ----------------
// P in LDS (32 KB, one barrier). M streamed from global: thread (cg=t&15,
// rg=t>>4) computes rows r0+rg*4..+3, cols cg*4..+3. The 16 cg-lanes of a
// row read identical M addresses (HW broadcast); lines live in L1 across
// the 8 consecutive kk-steps that reuse them. 16 f32 acc, no spill.
__global__ void __launch_bounds__(256) k_g2(const float* __restrict__ u_mul_s,
                                            const float* __restrict__ v_mul_s,
                                            const float* __restrict__ P,
                                            float* __restrict__ svd_u,
                                            float* __restrict__ svd_i) {
  __shared__ float Pl[Q * D];  // 32 KB, [k][c] stride 64
  const int mat = blockIdx.y;
  const float* __restrict__ M  = mat ? v_mul_s : u_mul_s;  // (N_U, 128)
  const float* __restrict__ Pg = mat ? P : (P + Q * D);
  float* __restrict__ outp     = mat ? svd_i : svd_u;
  const int t = threadIdx.x;
  // stage P: 2048 float4, 8 per thread, coalesced
#pragma unroll
  for (int i = 0; i < 8; ++i) {
    int idx = i * 256 + t;
    reinterpret_cast<float4*>(Pl)[idx] = reinterpret_cast<const float4*>(Pg)[idx];
  }
  __syncthreads();
  const int c0 = (t & 15) * 4;
  const int rbase = blockIdx.x * G2_ROWS + (t >> 4) * 4;
  // guarded row pointers (clamp to row 0 for OOB; store is guarded)
  const float4* mr0 = reinterpret_cast<const float4*>(M + (size_t)(rbase + 0 < N_U ? rbase + 0 : 0) * Q);
  const float4* mr1 = reinterpret_cast<const float4*>(M + (size_t)(rbase + 1 < N_U ? rbase + 1 : 0) * Q);
  const float4* mr2 = reinterpret_cast<const float4*>(M + (size_t)(rbase + 2 < N_U ? rbase + 2 : 0) * Q);
  const float4* mr3 = reinterpret_cast<const float4*>(M + (size_t)(rbase + 3 < N_U ? rbase + 3 : 0) * Q);
  float4 a0 = {0, 0, 0, 0}, a1 = {0, 0, 0, 0}, a2 = {0, 0, 0, 0}, a3 = {0, 0, 0, 0};
#pragma unroll 4
  for (int k4 = 0; k4 < Q / 4; ++k4) {
    float4 m0 = mr0[k4];
    float4 m1 = mr1[k4];
    float4 m2 = mr2[k4];
    float4 m3 = mr3[k4];
    float4 p0 = *reinterpret_cast<const float4*>(&Pl[(k4 * 4 + 0) * D + c0]);
    float4 p1 = *reinterpret_cast<const float4*>(&Pl[(k4 * 4 + 1) * D + c0]);
    float4 p2 = *reinterpret_cast<const float4*>(&Pl[(k4 * 4 + 2) * D + c0]);
    float4 p3 = *reinterpret_cast<const float4*>(&Pl[(k4 * 4 + 3) * D + c0]);
#define G2FMA(aj, mj)                                                                 \
  aj.x = fmaf(mj.x, p0.x, aj.x); aj.y = fmaf(mj.x, p0.y, aj.y);                       \
  aj.z = fmaf(mj.x, p0.z, aj.z); aj.w = fmaf(mj.x, p0.w, aj.w);                       \
  aj.x = fmaf(mj.y, p1.x, aj.x); aj.y = fmaf(mj.y, p1.y, aj.y);                       \
  aj.z = fmaf(mj.y, p1.z, aj.z); aj.w = fmaf(mj.y, p1.w, aj.w);                       \
  aj.x = fmaf(mj.z, p2.x, aj.x); aj.y = fmaf(mj.z, p2.y, aj.y);                       \
  aj.z = fmaf(mj.z, p2.z, aj.z); aj.w = fmaf(mj.z, p2.w, aj.w);                       \
  aj.x = fmaf(mj.w, p3.x, aj.x); aj.y = fmaf(mj.w, p3.y, aj.y);                       \
  aj.z = fmaf(mj.w, p3.z, aj.z); aj.w = fmaf(mj.w, p3.w, aj.w);
    G2FMA(a0, m0)
    G2FMA(a1, m1)
    G2FMA(a2, m2)
    G2FMA(a3, m3)
#undef G2FMA
  }
  if (rbase + 0 < N_U) *reinterpret_cast<float4*>(outp + (size_t)(rbase + 0) * D + c0) = a0;
  if (rbase + 1 < N_U) *reinterpret_cast<float4*>(outp + (size_t)(rbase + 1) * D + c0) = a1;
  if (rbase + 2 < N_U) *reinterpret_cast<float4*>(outp + (size_t)(rbase + 2) * D + c0) = a2;
  if (rbase + 3 < N_U) *reinterpret_cast<float4*>(outp + (size_t)(rbase + 3) * D + c0) = a3;
}

extern "C" void kernel_launch(void* const* d_in, const int* in_sizes, int n_in,
                              void* d_out, int out_size, void* d_ws, size_t ws_size,
                              hipStream_t stream) {
  const float* user_emb = (const float*)d_in[0];
  const float* item_emb = (const float*)d_in[1];
  const int*   adj_row  = (const int*)d_in[2];
  const int*   adj_col  = (const int*)d_in[3];
  const float* adj_vals = (const float*)d_in[4];
  const float* ut       = (const float*)d_in[5];
  const float* vt       = (const float*)d_in[6];
  const float* u_mul_s  = (const float*)d_in[7];
  const float* v_mul_s  = (const float*)d_in[8];
  float* out = (float*)d_out;

  char* ws = (char*)d_ws;
  size_t off = 0;
  auto alloc = [&](size_t bytes) -> void* {
    void* p = ws + off;
    off = (off + bytes + 255) & ~(size_t)255;
    return p;
  };
  unsigned short* eb0 = (unsigned short*)alloc((size_t)NTOT * D * 2);  // 25.6 MB
  unsigned short* eb1 = (unsigned short*)alloc((size_t)NTOT * D * 2);
  unsigned short* eb2 = (unsigned short*)alloc((size_t)NTOT * D * 2);
  unsigned short* eb3 = (unsigned short*)alloc((size_t)NTOT * D * 2);
  int2*  ebuck  = (int2*)alloc((size_t)NNZ * 8);                  // 25.6 MB
  int2*  edges  = (int2*)alloc((size_t)NNZ * 8);                  // 25.6 MB
  int*   rowptr = (int*)alloc((size_t)(NTOT + 1) * 4);
  int*   part   = (int*)alloc((size_t)P_NBLK * NBUCK * 4);        // 611 KB
  int*   outb   = (int*)alloc((size_t)P_NBLK * NBUCK * 4);        // 611 KB
  int*   bbase  = (int*)alloc((size_t)(NBUCK + 1) * 4);
  float* P      = (float*)alloc(2 * Q * D * 4);                   // 64 KB
  float* Ppart  = (float*)alloc((size_t)2 * G1_NBLK * Q * D * 4); // 16.4 MB

  float* mean_u = out;                   // seg0
  float* svd_u  = out + (size_t)SEG;     // seg1
  float* mean_i = out + 2 * (size_t)SEG; // seg2
  float* svd_i  = out + 3 * (size_t)SEG; // seg3

  // CSR build: atomic-free multisplit (bucket = row>>9)
  k_bhist<<<P_NBLK, 512, 0, stream>>>(adj_row, part);
  k_bscan<<<1, 512, 0, stream>>>(part, outb, bbase);
  k_mscat<<<P_NBLK, 512, 0, stream>>>(adj_row, adj_col, adj_vals, outb, bbase, ebuck);
  k_rsort<<<NBUCK, 512, 0, stream>>>(bbase, ebuck, edges, rowptr);

  // inputs -> bf16 concat ego
  k_cvt<<<(NTOT * D / 8 + 255) / 256, 256, 0, stream>>>(user_emb, item_emb, eb0);

  const int spmmGrid = (NTOT * 64) / 256;
  k_spmm<<<spmmGrid, 256, 0, stream>>>(rowptr, edges, eb0, eb1);
  k_spmm<<<spmmGrid, 256, 0, stream>>>(rowptr, edges, eb1, eb2);
  k_spmm<<<spmmGrid, 256, 0, stream>>>(rowptr, edges, eb2, eb3);

  // mean = (e1+e2+e3)/3 -> f32 segments
  k_mean<<<(NTOT * D / 8 + 255) / 256, 256, 0, stream>>>(eb1, eb2, eb3, mean_u, mean_i);

  // P_u partials (y=0, from mean_u/ut), P_v partials (y=1, from mean_i/vt)
  k_g1<<<dim3(G1_NBLK, 2), 512, 0, stream>>>(ut, vt, mean_u, mean_i, Ppart);
  k_reduce<<<(2 * Q * D + 255) / 256, 256, 0, stream>>>(Ppart, P);

  // y=0: svd_u = u_mul_s @ P_v ; y=1: svd_i = v_mul_s @ P_u
  k_g2<<<dim3(G2_NBLK, 2), 256, 0, stream>>>(u_mul_s, v_mul_s, P, svd_u, svd_i);
}

// Round 10
// 635.847 us; speedup vs baseline: 3.6163x; 1.0387x over previous
//
#include <hip/hip_runtime.h>

constexpr int N_U  = 100000;
constexpr int N_I  = 100000;
constexpr int NTOT = 200000;   // N_U + N_I
constexpr int D    = 64;
constexpr int Q    = 128;
constexpr int NNZ  = 3200000;
constexpr int SEG  = N_U * D;  // 6,400,000 floats per output segment

constexpr int G1_CHUNK = 400;
constexpr int G1_NBLK  = 250;  // ceil(100000/400)

// bucket sort params: bucket = row >> 9 (512 rows/bucket)
constexpr int BROWS   = 512;
constexpr int NBUCK   = (NTOT + BROWS - 1) / BROWS;  // 391
constexpr int P_CHUNK = 8192;                        // edges per P1/P3 block
constexpr int P_NBLK  = (NNZ + P_CHUNK - 1) / P_CHUNK;  // 391

// G2: 64 rows x 64 cols per block; P in LDS (32 KB), M streamed from global
constexpr int G2_ROWS = 64;
constexpr int G2_NBLK = (N_U + G2_ROWS - 1) / G2_ROWS;  // 1563

constexpr int CVT_CNT  = NTOT * D / 8;                  // 1.6M cvt work items
constexpr int CVT_BLKS = (CVT_CNT + 511) / 512;         // 3125

// bf16 helpers (RNE pack, shift unpack)
__device__ __forceinline__ unsigned short f2bf(float f) {
  unsigned int b = __float_as_uint(f);
  return (unsigned short)((b + 0x7fff + ((b >> 16) & 1)) >> 16);
}
__device__ __forceinline__ float bf2f(unsigned short u) {
  return __uint_as_float((unsigned int)u << 16);
}

// ---------------- P1 (fused): bucket histogram + input cvt -----------------
__global__ void __launch_bounds__(512) k_pre(const int* __restrict__ row,
                                             int* __restrict__ part,
                                             const float* __restrict__ user_emb,
                                             const float* __restrict__ item_emb,
                                             unsigned short* __restrict__ e0) {
  __shared__ int h[NBUCK];
  const int t = threadIdx.x;
  if (blockIdx.x < (unsigned)P_NBLK) {
    if (t < NBUCK) h[t] = 0;
    __syncthreads();
    const int e0i = blockIdx.x * P_CHUNK;
#pragma unroll
    for (int i = 0; i < P_CHUNK / 512; ++i) {
      int e = e0i + i * 512 + t;
      if (e < NNZ) atomicAdd(&h[row[e] >> 9], 1);
    }
    __syncthreads();
    if (t < NBUCK) part[blockIdx.x * NBUCK + t] = h[t];
  } else {
    int i = (blockIdx.x - P_NBLK) * 512 + t;
    if (i >= CVT_CNT) return;
    size_t base = (size_t)i * 8;
    const float* src = (base < (size_t)SEG) ? (user_emb + base) : (item_emb + base - SEG);
    float4 v0 = *reinterpret_cast<const float4*>(src);
    float4 v1 = *reinterpret_cast<const float4*>(src + 4);
    union { unsigned short us[8]; uint4 u4; } pk;
    pk.us[0] = f2bf(v0.x); pk.us[1] = f2bf(v0.y); pk.us[2] = f2bf(v0.z); pk.us[3] = f2bf(v0.w);
    pk.us[4] = f2bf(v1.x); pk.us[5] = f2bf(v1.y); pk.us[6] = f2bf(v1.z); pk.us[7] = f2bf(v1.w);
    *reinterpret_cast<uint4*>(e0 + base) = pk.u4;
  }
}

// ---------------- P2a: per-bucket column scan (one wave per bucket) --------
__global__ void __launch_bounds__(64) k_bscanA(const int* __restrict__ part,
                                               int* __restrict__ outb,
                                               int* __restrict__ btot) {
  const int b = blockIdx.x;
  const int l = threadIdx.x;
  int carry = 0;
#pragma unroll
  for (int round = 0; round < (P_NBLK + 63) / 64; ++round) {
    int blk = round * 64 + l;
    int v = (blk < P_NBLK) ? part[blk * NBUCK + b] : 0;
    int x = v;
#pragma unroll
    for (int off = 1; off < 64; off <<= 1) {
      int y = __shfl_up(x, off, 64);
      if (l >= off) x += y;
    }
    if (blk < P_NBLK) outb[blk * NBUCK + b] = carry + x - v;
    carry += __shfl(x, 63, 64);
  }
  if (l == 0) btot[b] = carry;
}

// ---------------- P2b: bucket-total scan -> bbase --------------------------
__global__ void __launch_bounds__(512) k_bscanB(const int* __restrict__ btot,
                                                int* __restrict__ bbase) {
  __shared__ int s[512];
  const int t = threadIdx.x;
  const int own = (t < NBUCK) ? btot[t] : 0;
  s[t] = own;
  __syncthreads();
  for (int off = 1; off < 512; off <<= 1) {
    int y = (t >= off) ? s[t - off] : 0;
    __syncthreads();
    s[t] += y;
    __syncthreads();
  }
  if (t <= NBUCK) bbase[t] = s[t] - own;  // bbase[NBUCK] == NNZ
}

// ---------------- P3: scatter edges to bucket-grouped ebuck ----------------
__global__ void __launch_bounds__(512) k_mscat(const int* __restrict__ row,
                                               const int* __restrict__ col,
                                               const float* __restrict__ val,
                                               const int* __restrict__ outb,
                                               const int* __restrict__ bbase,
                                               int2* __restrict__ ebuck) {
  __shared__ int cur[NBUCK];
  const int t = threadIdx.x;
  if (t < NBUCK) cur[t] = bbase[t] + outb[blockIdx.x * NBUCK + t];
  __syncthreads();
  const int e0 = blockIdx.x * P_CHUNK;
#pragma unroll
  for (int i = 0; i < P_CHUNK / 512; ++i) {
    int e = e0 + i * 512 + t;
    if (e < NNZ) {
      int r = row[e];
      int b = r >> 9;
      int pos = atomicAdd(&cur[b], 1);
      ebuck[pos] = make_int2(col[e] | ((r & (BROWS - 1)) << 18), __float_as_int(val[e]));
    }
  }
}

// ---------------- P4: within-bucket row sort + rowptr emission -------------
__global__ void __launch_bounds__(512) k_rsort(const int* __restrict__ bbase,
                                               const int2* __restrict__ ebuck,
                                               int2* __restrict__ edges,
                                               int* __restrict__ rowptr) {
  __shared__ int s[512];
  __shared__ int cur[512];
  const int t = threadIdx.x;
  const int b = blockIdx.x;
  const int eb0 = bbase[b], eb1 = bbase[b + 1];
  cur[t] = 0;
  __syncthreads();
  for (int e = eb0 + t; e < eb1; e += 512) atomicAdd(&cur[ebuck[e].x >> 18], 1);
  __syncthreads();
  const int own = cur[t];
  s[t] = own;
  __syncthreads();
  for (int off = 1; off < 512; off <<= 1) {
    int y = (t >= off) ? s[t - off] : 0;
    __syncthreads();
    s[t] += y;
    __syncthreads();
  }
  const int excl = s[t] - own;
  const int r = (b << 9) + t;
  if (r < NTOT) rowptr[r] = eb0 + excl;
  if (b == NBUCK - 1 && t == 0) rowptr[NTOT] = NNZ;
  cur[t] = eb0 + excl;
  __syncthreads();
  for (int e = eb0 + t; e < eb1; e += 512) {
    int2 kv = ebuck[e];
    int pos = atomicAdd(&cur[kv.x >> 18], 1);
    edges[pos] = make_int2(kv.x & 0x3FFFF, kv.y);
  }
}

// ---------------- SpMM bf16, 16-deep MLP; FINAL fuses the mean -------------
// FINAL=0: dst[r] = bf16(sum)   (nontemporal store)
// FINAL=1: mean = (bf2f(p1)+bf2f(p2)+sum)/3 -> f32 out segments
template <int FINAL>
__global__ void k_spmm(const int* __restrict__ rowptr, const int2* __restrict__ edges,
                       const unsigned short* __restrict__ src,
                       unsigned short* __restrict__ dst,
                       const unsigned short* __restrict__ p1,
                       const unsigned short* __restrict__ p2,
                       float* __restrict__ mean_u, float* __restrict__ mean_i) {
  const int r = (blockIdx.x * 256 + threadIdx.x) >> 6;
  const int lane = threadIdx.x & 63;
  if (r >= NTOT) return;
  const int eb = rowptr[r], ee = rowptr[r + 1];
  float sA = 0.f, sB = 0.f;
  int e = eb;
#define GIDX(dd) ((unsigned)(((dd).x << 6) + lane))
  for (; e + 16 <= ee; e += 16) {
    int2 d0 = edges[e + 0], d1 = edges[e + 1], d2 = edges[e + 2], d3 = edges[e + 3];
    int2 d4 = edges[e + 4], d5 = edges[e + 5], d6 = edges[e + 6], d7 = edges[e + 7];
    int2 d8 = edges[e + 8], d9 = edges[e + 9], da = edges[e + 10], db = edges[e + 11];
    int2 dc = edges[e + 12], dd = edges[e + 13], de = edges[e + 14], df = edges[e + 15];
    unsigned short u0 = src[GIDX(d0)], u1 = src[GIDX(d1)], u2 = src[GIDX(d2)], u3 = src[GIDX(d3)];
    unsigned short u4 = src[GIDX(d4)], u5 = src[GIDX(d5)], u6 = src[GIDX(d6)], u7 = src[GIDX(d7)];
    unsigned short u8 = src[GIDX(d8)], u9 = src[GIDX(d9)], ua = src[GIDX(da)], ub = src[GIDX(db)];
    unsigned short uc = src[GIDX(dc)], ud = src[GIDX(dd)], ue = src[GIDX(de)], uf = src[GIDX(df)];
    sA = fmaf(__int_as_float(d0.y), bf2f(u0), sA);
    sB = fmaf(__int_as_float(d1.y), bf2f(u1), sB);
    sA = fmaf(__int_as_float(d2.y), bf2f(u2), sA);
    sB = fmaf(__int_as_float(d3.y), bf2f(u3), sB);
    sA = fmaf(__int_as_float(d4.y), bf2f(u4), sA);
    sB = fmaf(__int_as_float(d5.y), bf2f(u5), sB);
    sA = fmaf(__int_as_float(d6.y), bf2f(u6), sA);
    sB = fmaf(__int_as_float(d7.y), bf2f(u7), sB);
    sA = fmaf(__int_as_float(d8.y), bf2f(u8), sA);
    sB = fmaf(__int_as_float(d9.y), bf2f(u9), sB);
    sA = fmaf(__int_as_float(da.y), bf2f(ua), sA);
    sB = fmaf(__int_as_float(db.y), bf2f(ub), sB);
    sA = fmaf(__int_as_float(dc.y), bf2f(uc), sA);
    sB = fmaf(__int_as_float(dd.y), bf2f(ud), sB);
    sA = fmaf(__int_as_float(de.y), bf2f(ue), sA);
    sB = fmaf(__int_as_float(df.y), bf2f(uf), sB);
  }
  for (; e + 4 <= ee; e += 4) {
    int2 d0 = edges[e + 0], d1 = edges[e + 1], d2 = edges[e + 2], d3 = edges[e + 3];
    unsigned short u0 = src[GIDX(d0)], u1 = src[GIDX(d1)], u2 = src[GIDX(d2)], u3 = src[GIDX(d3)];
    sA = fmaf(__int_as_float(d0.y), bf2f(u0), sA);
    sB = fmaf(__int_as_float(d1.y), bf2f(u1), sB);
    sA = fmaf(__int_as_float(d2.y), bf2f(u2), sA);
    sB = fmaf(__int_as_float(d3.y), bf2f(u3), sB);
  }
  for (; e < ee; ++e) {
    int2 d0 = edges[e];
    sA = fmaf(__int_as_float(d0.y), bf2f(src[GIDX(d0)]), sA);
  }
#undef GIDX
  const float sum = sA + sB;
  const unsigned idx = ((unsigned)r << 6) + lane;
  if (!FINAL) {
    __builtin_nontemporal_store(f2bf(sum), &dst[idx]);
  } else {
    float m = (bf2f(p1[idx]) + bf2f(p2[idx]) + sum) * (1.f / 3.f);
    if (r < N_U) mean_u[idx] = m;
    else         mean_i[idx - (unsigned)SEG] = m;
  }
}

// ---------------- G1: Ppart[mat][blk] = W(128 x nchunk) @ X(nchunk x 64) ----
__global__ void __launch_bounds__(512) k_g1(const float* __restrict__ ut,
                                            const float* __restrict__ vt,
                                            const float* __restrict__ accu,
                                            const float* __restrict__ acci,
                                            float* __restrict__ Ppart) {
  __shared__ float Wl[128 * 65];
  __shared__ float Xl[64 * 64];
  const int mat = blockIdx.y;
  const float* __restrict__ W = mat ? vt : ut;      // (Q, N_U) row-major
  const float* __restrict__ X = mat ? acci : accu;  // (N_U, 64) holds mean
  const int t = threadIdx.x;
  const int q0 = (t >> 4) * 4;   // 32 q-groups
  const int d0 = (t & 15) * 4;   // 16 d-groups
  const int n0 = blockIdx.x * G1_CHUNK;
  const int n1 = min(n0 + G1_CHUNK, N_U);
  float4 a0 = {0, 0, 0, 0}, a1 = {0, 0, 0, 0}, a2 = {0, 0, 0, 0}, a3 = {0, 0, 0, 0};
  for (int k = n0; k < n1; k += 64) {
#pragma unroll
    for (int rep = 0; rep < 2; ++rep) {
      int f4 = t + rep * 512;
      int row = f4 >> 4;
      int c4 = (f4 & 15) * 4;
      int gr = k + row;
      float4 v = (gr < n1) ? *reinterpret_cast<const float4*>(X + (size_t)gr * 64 + c4)
                           : float4{0, 0, 0, 0};
      *reinterpret_cast<float4*>(&Xl[row * 64 + c4]) = v;
    }
    {
      int q = t >> 2;
      int c16 = (t & 3) * 16;
#pragma unroll
      for (int jj = 0; jj < 4; ++jj) {
        int kk = c16 + jj * 4;
        int gk = k + kk;
        float4 v = (gk < n1) ? *reinterpret_cast<const float4*>(W + (size_t)q * N_U + gk)
                             : float4{0, 0, 0, 0};
        *reinterpret_cast<float4*>(&Wl[q * 65 + kk]) = v;
      }
    }
    __syncthreads();
#pragma unroll 2
    for (int kk = 0; kk < 64; kk += 4) {
      float4 w0 = *reinterpret_cast<const float4*>(&Wl[(q0 + 0) * 65 + kk]);
      float4 w1 = *reinterpret_cast<const float4*>(&Wl[(q0 + 1) * 65 + kk]);
      float4 w2 = *reinterpret_cast<const float4*>(&Wl[(q0 + 2) * 65 + kk]);
      float4 w3 = *reinterpret_cast<const float4*>(&Wl[(q0 + 3) * 65 + kk]);
      float4 x0 = *reinterpret_cast<const float4*>(&Xl[(kk + 0) * 64 + d0]);
      float4 x1 = *reinterpret_cast<const float4*>(&Xl[(kk + 1) * 64 + d0]);
      float4 x2 = *reinterpret_cast<const float4*>(&Xl[(kk + 2) * 64 + d0]);
      float4 x3 = *reinterpret_cast<const float4*>(&Xl[(kk + 3) * 64 + d0]);
#define FMA16(aj, wj)                                                                 \
  aj.x = fmaf(wj.x, x0.x, aj.x); aj.y = fmaf(wj.x, x0.y, aj.y);                       \
  aj.z = fmaf(wj.x, x0.z, aj.z); aj.w = fmaf(wj.x, x0.w, aj.w);                       \
  aj.x = fmaf(wj.y, x1.x, aj.x); aj.y = fmaf(wj.y, x1.y, aj.y);                       \
  aj.z = fmaf(wj.y, x1.z, aj.z); aj.w = fmaf(wj.y, x1.w, aj.w);                       \
  aj.x = fmaf(wj.z, x2.x, aj.x); aj.y = fmaf(wj.z, x2.y, aj.y);                       \
  aj.z = fmaf(wj.z, x2.z, aj.z); aj.w = fmaf(wj.z, x2.w, aj.w);                       \
  aj.x = fmaf(wj.w, x3.x, aj.x); aj.y = fmaf(wj.w, x3.y, aj.y);                       \
  aj.z = fmaf(wj.w, x3.z, aj.z); aj.w = fmaf(wj.w, x3.w, aj.w);
      FMA16(a0, w0)
      FMA16(a1, w1)
      FMA16(a2, w2)
      FMA16(a3, w3)
#undef FMA16
    }
    __syncthreads();
  }
  float* dst = Ppart + ((size_t)mat * G1_NBLK + blockIdx.x) * (Q * D);
  *reinterpret_cast<float4*>(dst + (q0 + 0) * 64 + d0) = a0;
  *reinterpret_cast<float4*>(dst + (q0 + 1) * 64 + d0) = a1;
  *reinterpret_cast<float4*>(dst + (q0 + 2) * 64 + d0) = a2;
  *reinterpret_cast<float4*>(dst + (q0 + 3) * 64 + d0) = a3;
}

// P[mat][q][d] = 3 * sum_blk Ppart[mat][blk][q][d]
__global__ void k_reduce(const float* __restrict__ Ppart, float* __restrict__ P) {
  int idx = blockIdx.x * 256 + threadIdx.x;  // 0..16383
  if (idx >= 2 * Q * D) return;
  int mat = idx >> 13;
  int qd = idx & (Q * D - 1);
  const float* src = Ppart + (size_t)mat * G1_NBLK * (Q * D) + qd;
  float s = 0.f;
#pragma unroll 4
  for (int b = 0; b < G1_NBLK; ++b) s += src[(size_t)b * (Q * D)];
  P[idx] = s * 3.f;
}

// ---------------- G2: out(N x 64) = M(N x 128) @ P(128 x 64) ----------------
__global__ void __launch_bounds__(256) k_g2(const float* __restrict__ u_mul_s,
                                            const float* __restrict__ v_mul_s,
                                            const float* __restrict__ P,
                                            float* __restrict__ svd_u,
                                            float* __restrict__ svd_i) {
  __shared__ float Pl[Q * D];  // 32 KB, [k][c] stride 64
  const int mat = blockIdx.y;
  const float* __restrict__ M  = mat ? v_mul_s : u_mul_s;  // (N_U, 128)
  const float* __restrict__ Pg = mat ? P : (P + Q * D);
  float* __restrict__ outp     = mat ? svd_i : svd_u;
  const int t = threadIdx.x;
#pragma unroll
  for (int i = 0; i < 8; ++i) {
    int idx = i * 256 + t;
    reinterpret_cast<float4*>(Pl)[idx] = reinterpret_cast<const float4*>(Pg)[idx];
  }
  __syncthreads();
  const int c0 = (t & 15) * 4;
  const int rbase = blockIdx.x * G2_ROWS + (t >> 4) * 4;
  const float4* mr0 = reinterpret_cast<const float4*>(M + (size_t)(rbase + 0 < N_U ? rbase + 0 : 0) * Q);
  const float4* mr1 = reinterpret_cast<const float4*>(M + (size_t)(rbase + 1 < N_U ? rbase + 1 : 0) * Q);
  const float4* mr2 = reinterpret_cast<const float4*>(M + (size_t)(rbase + 2 < N_U ? rbase + 2 : 0) * Q);
  const float4* mr3 = reinterpret_cast<const float4*>(M + (size_t)(rbase + 3 < N_U ? rbase + 3 : 0) * Q);
  float4 a0 = {0, 0, 0, 0}, a1 = {0, 0, 0, 0}, a2 = {0, 0, 0, 0}, a3 = {0, 0, 0, 0};
#pragma unroll 4
  for (int k4 = 0; k4 < Q / 4; ++k4) {
    float4 m0 = mr0[k4];
    float4 m1 = mr1[k4];
    float4 m2 = mr2[k4];
    float4 m3 = mr3[k4];
    float4 p0 = *reinterpret_cast<const float4*>(&Pl[(k4 * 4 + 0) * D + c0]);
    float4 p1 = *reinterpret_cast<const float4*>(&Pl[(k4 * 4 + 1) * D + c0]);
    float4 p2 = *reinterpret_cast<const float4*>(&Pl[(k4 * 4 + 2) * D + c0]);
    float4 p3 = *reinterpret_cast<const float4*>(&Pl[(k4 * 4 + 3) * D + c0]);
#define G2FMA(aj, mj)                                                                 \
  aj.x = fmaf(mj.x, p0.x, aj.x); aj.y = fmaf(mj.x, p0.y, aj.y);                       \
  aj.z = fmaf(mj.x, p0.z, aj.z); aj.w = fmaf(mj.x, p0.w, aj.w);                       \
  aj.x = fmaf(mj.y, p1.x, aj.x); aj.y = fmaf(mj.y, p1.y, aj.y);                       \
  aj.z = fmaf(mj.y, p1.z, aj.z); aj.w = fmaf(mj.y, p1.w, aj.w);                       \
  aj.x = fmaf(mj.z, p2.x, aj.x); aj.y = fmaf(mj.z, p2.y, aj.y);                       \
  aj.z = fmaf(mj.z, p2.z, aj.z); aj.w = fmaf(mj.z, p2.w, aj.w);                       \
  aj.x = fmaf(mj.w, p3.x, aj.x); aj.y = fmaf(mj.w, p3.y, aj.y);                       \
  aj.z = fmaf(mj.w, p3.z, aj.z); aj.w = fmaf(mj.w, p3.w, aj.w);
    G2FMA(a0, m0)
    G2FMA(a1, m1)
    G2FMA(a2, m2)
    G2FMA(a3, m3)
#undef G2FMA
  }
  if (rbase + 0 < N_U) *reinterpret_cast<float4*>(outp + (size_t)(rbase + 0) * D + c0) = a0;
  if (rbase + 1 < N_U) *reinterpret_cast<float4*>(outp + (size_t)(rbase + 1) * D + c0) = a1;
  if (rbase + 2 < N_U) *reinterpret_cast<float4*>(outp + (size_t)(rbase + 2) * D + c0) = a2;
  if (rbase + 3 < N_U) *reinterpret_cast<float4*>(outp + (size_t)(rbase + 3) * D + c0) = a3;
}

extern "C" void kernel_launch(void* const* d_in, const int* in_sizes, int n_in,
                              void* d_out, int out_size, void* d_ws, size_t ws_size,
                              hipStream_t stream) {
  const float* user_emb = (const float*)d_in[0];
  const float* item_emb = (const float*)d_in[1];
  const int*   adj_row  = (const int*)d_in[2];
  const int*   adj_col  = (const int*)d_in[3];
  const float* adj_vals = (const float*)d_in[4];
  const float* ut       = (const float*)d_in[5];
  const float* vt       = (const float*)d_in[6];
  const float* u_mul_s  = (const float*)d_in[7];
  const float* v_mul_s  = (const float*)d_in[8];
  float* out = (float*)d_out;

  char* ws = (char*)d_ws;
  size_t off = 0;
  auto alloc = [&](size_t bytes) -> void* {
    void* p = ws + off;
    off = (off + bytes + 255) & ~(size_t)255;
    return p;
  };
  unsigned short* eb0 = (unsigned short*)alloc((size_t)NTOT * D * 2);  // 25.6 MB
  unsigned short* eb1 = (unsigned short*)alloc((size_t)NTOT * D * 2);
  unsigned short* eb2 = (unsigned short*)alloc((size_t)NTOT * D * 2);
  int2*  ebuck  = (int2*)alloc((size_t)NNZ * 8);                  // 25.6 MB
  int2*  edges  = (int2*)alloc((size_t)NNZ * 8);                  // 25.6 MB
  int*   rowptr = (int*)alloc((size_t)(NTOT + 1) * 4);
  int*   part   = (int*)alloc((size_t)P_NBLK * NBUCK * 4);        // 611 KB
  int*   outb   = (int*)alloc((size_t)P_NBLK * NBUCK * 4);        // 611 KB
  int*   btot   = (int*)alloc((size_t)NBUCK * 4);
  int*   bbase  = (int*)alloc((size_t)(NBUCK + 1) * 4);
  float* P      = (float*)alloc(2 * Q * D * 4);                   // 64 KB
  float* Ppart  = (float*)alloc((size_t)2 * G1_NBLK * Q * D * 4); // 16.4 MB

  float* mean_u = out;                   // seg0
  float* svd_u  = out + (size_t)SEG;     // seg1
  float* mean_i = out + 2 * (size_t)SEG; // seg2
  float* svd_i  = out + 3 * (size_t)SEG; // seg3

  // CSR build (atomic-free multisplit) + fused input cvt
  k_pre<<<P_NBLK + CVT_BLKS, 512, 0, stream>>>(adj_row, part, user_emb, item_emb, eb0);
  k_bscanA<<<NBUCK, 64, 0, stream>>>(part, outb, btot);
  k_bscanB<<<1, 512, 0, stream>>>(btot, bbase);
  k_mscat<<<P_NBLK, 512, 0, stream>>>(adj_row, adj_col, adj_vals, outb, bbase, ebuck);
  k_rsort<<<NBUCK, 512, 0, stream>>>(bbase, ebuck, edges, rowptr);

  const int spmmGrid = (NTOT * 64) / 256;
  k_spmm<0><<<spmmGrid, 256, 0, stream>>>(rowptr, edges, eb0, eb1, nullptr, nullptr,
                                          nullptr, nullptr);
  k_spmm<0><<<spmmGrid, 256, 0, stream>>>(rowptr, edges, eb1, eb2, nullptr, nullptr,
                                          nullptr, nullptr);
  // layer 3 fused with mean: reads e1,e2 coalesced, writes f32 mean segments
  k_spmm<1><<<spmmGrid, 256, 0, stream>>>(rowptr, edges, eb2, nullptr, eb1, eb2,
                                          mean_u, mean_i);

  // P_u partials (y=0, from mean_u/ut), P_v partials (y=1, from mean_i/vt)
  k_g1<<<dim3(G1_NBLK, 2), 512, 0, stream>>>(ut, vt, mean_u, mean_i, Ppart);
  k_reduce<<<(2 * Q * D + 255) / 256, 256, 0, stream>>>(Ppart, P);

  // y=0: svd_u = u_mul_s @ P_v ; y=1: svd_i = v_mul_s @ P_u
  k_g2<<<dim3(G2_NBLK, 2), 256, 0, stream>>>(u_mul_s, v_mul_s, P, svd_u, svd_i);
}

// Round 11
// 578.442 us; speedup vs baseline: 3.9752x; 1.0992x over previous
//
#include <hip/hip_runtime.h>

constexpr int N_U  = 100000;
constexpr int N_I  = 100000;
constexpr int NTOT = 200000;   // N_U + N_I
constexpr int D    = 64;
constexpr int Q    = 128;
constexpr int NNZ  = 3200000;
constexpr int SEG  = N_U * D;  // 6,400,000 floats per output segment

constexpr int G1_CHUNK = 400;
constexpr int G1_NBLK  = 250;  // ceil(100000/400)

// bucket sort params: bucket = row >> 9 (512 rows/bucket)
constexpr int BROWS   = 512;
constexpr int NBUCK   = (NTOT + BROWS - 1) / BROWS;  // 391
constexpr int P_CHUNK = 8192;                        // edges per P1/P3 block
constexpr int P_NBLK  = (NNZ + P_CHUNK - 1) / P_CHUNK;  // 391

// G2: 64 rows x 64 cols per block; P in LDS (32 KB), M streamed from global
constexpr int G2_ROWS = 64;
constexpr int G2_NBLK = (N_U + G2_ROWS - 1) / G2_ROWS;  // 1563

constexpr int CVT_CNT  = NTOT * D / 8;                  // 1.6M cvt work items
constexpr int CVT_BLKS = (CVT_CNT + 511) / 512;         // 3125

// bf16 helpers (RNE pack, shift unpack)
__device__ __forceinline__ unsigned short f2bf(float f) {
  unsigned int b = __float_as_uint(f);
  return (unsigned short)((b + 0x7fff + ((b >> 16) & 1)) >> 16);
}
__device__ __forceinline__ float bf2f(unsigned short u) {
  return __uint_as_float((unsigned int)u << 16);
}
// unpack a u32 holding 2 bf16 (little-endian: low half = even elem)
__device__ __forceinline__ float bflo(unsigned u) { return __uint_as_float(u << 16); }
__device__ __forceinline__ float bfhi(unsigned u) { return __uint_as_float(u & 0xffff0000u); }

// ---------------- P1 (fused): bucket histogram + input cvt -----------------
__global__ void __launch_bounds__(512) k_pre(const int* __restrict__ row,
                                             int* __restrict__ part,
                                             const float* __restrict__ user_emb,
                                             const float* __restrict__ item_emb,
                                             unsigned short* __restrict__ e0) {
  __shared__ int h[NBUCK];
  const int t = threadIdx.x;
  if (blockIdx.x < (unsigned)P_NBLK) {
    if (t < NBUCK) h[t] = 0;
    __syncthreads();
    const int e0i = blockIdx.x * P_CHUNK;
#pragma unroll
    for (int i = 0; i < P_CHUNK / 512; ++i) {
      int e = e0i + i * 512 + t;
      if (e < NNZ) atomicAdd(&h[row[e] >> 9], 1);
    }
    __syncthreads();
    if (t < NBUCK) part[blockIdx.x * NBUCK + t] = h[t];
  } else {
    int i = (blockIdx.x - P_NBLK) * 512 + t;
    if (i >= CVT_CNT) return;
    size_t base = (size_t)i * 8;
    const float* src = (base < (size_t)SEG) ? (user_emb + base) : (item_emb + base - SEG);
    float4 v0 = *reinterpret_cast<const float4*>(src);
    float4 v1 = *reinterpret_cast<const float4*>(src + 4);
    union { unsigned short us[8]; uint4 u4; } pk;
    pk.us[0] = f2bf(v0.x); pk.us[1] = f2bf(v0.y); pk.us[2] = f2bf(v0.z); pk.us[3] = f2bf(v0.w);
    pk.us[4] = f2bf(v1.x); pk.us[5] = f2bf(v1.y); pk.us[6] = f2bf(v1.z); pk.us[7] = f2bf(v1.w);
    *reinterpret_cast<uint4*>(e0 + base) = pk.u4;
  }
}

// ---------------- P2a: per-bucket column scan (one wave per bucket) --------
__global__ void __launch_bounds__(64) k_bscanA(const int* __restrict__ part,
                                               int* __restrict__ outb,
                                               int* __restrict__ btot) {
  const int b = blockIdx.x;
  const int l = threadIdx.x;
  int carry = 0;
#pragma unroll
  for (int round = 0; round < (P_NBLK + 63) / 64; ++round) {
    int blk = round * 64 + l;
    int v = (blk < P_NBLK) ? part[blk * NBUCK + b] : 0;
    int x = v;
#pragma unroll
    for (int off = 1; off < 64; off <<= 1) {
      int y = __shfl_up(x, off, 64);
      if (l >= off) x += y;
    }
    if (blk < P_NBLK) outb[blk * NBUCK + b] = carry + x - v;
    carry += __shfl(x, 63, 64);
  }
  if (l == 0) btot[b] = carry;
}

// ---------------- P2b: bucket-total scan -> bbase --------------------------
__global__ void __launch_bounds__(512) k_bscanB(const int* __restrict__ btot,
                                                int* __restrict__ bbase) {
  __shared__ int s[512];
  const int t = threadIdx.x;
  const int own = (t < NBUCK) ? btot[t] : 0;
  s[t] = own;
  __syncthreads();
  for (int off = 1; off < 512; off <<= 1) {
    int y = (t >= off) ? s[t - off] : 0;
    __syncthreads();
    s[t] += y;
    __syncthreads();
  }
  if (t <= NBUCK) bbase[t] = s[t] - own;  // bbase[NBUCK] == NNZ
}

// ---------------- P3: scatter edges to bucket-grouped ebuck ----------------
__global__ void __launch_bounds__(512) k_mscat(const int* __restrict__ row,
                                               const int* __restrict__ col,
                                               const float* __restrict__ val,
                                               const int* __restrict__ outb,
                                               const int* __restrict__ bbase,
                                               int2* __restrict__ ebuck) {
  __shared__ int cur[NBUCK];
  const int t = threadIdx.x;
  if (t < NBUCK) cur[t] = bbase[t] + outb[blockIdx.x * NBUCK + t];
  __syncthreads();
  const int e0 = blockIdx.x * P_CHUNK;
#pragma unroll
  for (int i = 0; i < P_CHUNK / 512; ++i) {
    int e = e0 + i * 512 + t;
    if (e < NNZ) {
      int r = row[e];
      int b = r >> 9;
      int pos = atomicAdd(&cur[b], 1);
      ebuck[pos] = make_int2(col[e] | ((r & (BROWS - 1)) << 18), __float_as_int(val[e]));
    }
  }
}

// ---------------- P4: within-bucket row sort + rowptr emission -------------
__global__ void __launch_bounds__(512) k_rsort(const int* __restrict__ bbase,
                                               const int2* __restrict__ ebuck,
                                               int2* __restrict__ edges,
                                               int* __restrict__ rowptr) {
  __shared__ int s[512];
  __shared__ int cur[512];
  const int t = threadIdx.x;
  const int b = blockIdx.x;
  const int eb0 = bbase[b], eb1 = bbase[b + 1];
  cur[t] = 0;
  __syncthreads();
  for (int e = eb0 + t; e < eb1; e += 512) atomicAdd(&cur[ebuck[e].x >> 18], 1);
  __syncthreads();
  const int own = cur[t];
  s[t] = own;
  __syncthreads();
  for (int off = 1; off < 512; off <<= 1) {
    int y = (t >= off) ? s[t - off] : 0;
    __syncthreads();
    s[t] += y;
    __syncthreads();
  }
  const int excl = s[t] - own;
  const int r = (b << 9) + t;
  if (r < NTOT) rowptr[r] = eb0 + excl;
  if (b == NBUCK - 1 && t == 0) rowptr[NTOT] = NNZ;
  cur[t] = eb0 + excl;
  __syncthreads();
  for (int e = eb0 + t; e < eb1; e += 512) {
    int2 kv = ebuck[e];
    int pos = atomicAdd(&cur[kv.x >> 18], 1);
    edges[pos] = make_int2(kv.x & 0x3FFFF, kv.y);
  }
}

// ---------------- SpMM bf16: 2 rows/wave, 32 lanes/row, u32 gathers --------
// Lane l (=t&31) of half h handles elems 2l,2l+1 of row r = 2*wid + h.
// 8-deep edge pipeline per row; one vector load covers both rows' edges.
// FINAL=0: dst = bf16x2(sum)  (nontemporal)
// FINAL=1: mean = (p1+p2+sum)/3 -> f32 out segments
template <int FINAL>
__global__ void __launch_bounds__(256) k_spmm(
    const int* __restrict__ rowptr, const int2* __restrict__ edges,
    const unsigned* __restrict__ src32, unsigned* __restrict__ dst32,
    const unsigned* __restrict__ p1, const unsigned* __restrict__ p2,
    float* __restrict__ mean_u, float* __restrict__ mean_i) {
  const int wid = (blockIdx.x * 256 + threadIdx.x) >> 6;
  const int half = (threadIdx.x >> 5) & 1;
  const int l = threadIdx.x & 31;
  const int r = wid * 2 + half;
  if (r >= NTOT) return;
  const int eb = rowptr[r], ee = rowptr[r + 1];
  const unsigned long long* __restrict__ e64 =
      reinterpret_cast<const unsigned long long*>(edges);
  float s0 = 0.f, s1 = 0.f;
  int e = eb;
#define EDGE(q) unsigned long long q
#define LD(q, i) q = __builtin_nontemporal_load(&e64[e + i])
#define GA(u, q) unsigned u = src32[(((unsigned)(unsigned int)(q)) << 5) + l]
#define FMA(q, u)                                                     \
  {                                                                   \
    float v = __uint_as_float((unsigned)((q) >> 32));                 \
    s0 = fmaf(v, bflo(u), s0);                                        \
    s1 = fmaf(v, bfhi(u), s1);                                        \
  }
  for (; e + 8 <= ee; e += 8) {
    EDGE(q0); EDGE(q1); EDGE(q2); EDGE(q3); EDGE(q4); EDGE(q5); EDGE(q6); EDGE(q7);
    LD(q0, 0); LD(q1, 1); LD(q2, 2); LD(q3, 3);
    LD(q4, 4); LD(q5, 5); LD(q6, 6); LD(q7, 7);
    GA(u0, q0); GA(u1, q1); GA(u2, q2); GA(u3, q3);
    GA(u4, q4); GA(u5, q5); GA(u6, q6); GA(u7, q7);
    FMA(q0, u0) FMA(q1, u1) FMA(q2, u2) FMA(q3, u3)
    FMA(q4, u4) FMA(q5, u5) FMA(q6, u6) FMA(q7, u7)
  }
  for (; e + 2 <= ee; e += 2) {
    EDGE(q0); EDGE(q1);
    LD(q0, 0); LD(q1, 1);
    GA(u0, q0); GA(u1, q1);
    FMA(q0, u0) FMA(q1, u1)
  }
  if (e < ee) {
    EDGE(q0);
    LD(q0, 0);
    GA(u0, q0);
    FMA(q0, u0)
  }
#undef EDGE
#undef LD
#undef GA
#undef FMA
  const unsigned idx = ((unsigned)r << 5) + l;
  if (!FINAL) {
    unsigned pk = (unsigned)f2bf(s0) | ((unsigned)f2bf(s1) << 16);
    __builtin_nontemporal_store(pk, &dst32[idx]);
  } else {
    unsigned a = __builtin_nontemporal_load(&p1[idx]);
    unsigned b = __builtin_nontemporal_load(&p2[idx]);
    float m0 = (bflo(a) + bflo(b) + s0) * (1.f / 3.f);
    float m1 = (bfhi(a) + bfhi(b) + s1) * (1.f / 3.f);
    float* dstp = (r < N_U) ? (mean_u + ((size_t)r << 6) + l * 2)
                            : (mean_i + (((size_t)(r - N_U)) << 6) + l * 2);
    dstp[0] = m0;
    dstp[1] = m1;
  }
}

// ---------------- G1: Ppart[mat][blk] = W(128 x nchunk) @ X(nchunk x 64) ----
__global__ void __launch_bounds__(512) k_g1(const float* __restrict__ ut,
                                            const float* __restrict__ vt,
                                            const float* __restrict__ accu,
                                            const float* __restrict__ acci,
                                            float* __restrict__ Ppart) {
  __shared__ float Wl[128 * 65];
  __shared__ float Xl[64 * 64];
  const int mat = blockIdx.y;
  const float* __restrict__ W = mat ? vt : ut;      // (Q, N_U) row-major
  const float* __restrict__ X = mat ? acci : accu;  // (N_U, 64) holds mean
  const int t = threadIdx.x;
  const int q0 = (t >> 4) * 4;   // 32 q-groups
  const int d0 = (t & 15) * 4;   // 16 d-groups
  const int n0 = blockIdx.x * G1_CHUNK;
  const int n1 = min(n0 + G1_CHUNK, N_U);
  float4 a0 = {0, 0, 0, 0}, a1 = {0, 0, 0, 0}, a2 = {0, 0, 0, 0}, a3 = {0, 0, 0, 0};
  for (int k = n0; k < n1; k += 64) {
#pragma unroll
    for (int rep = 0; rep < 2; ++rep) {
      int f4 = t + rep * 512;
      int row = f4 >> 4;
      int c4 = (f4 & 15) * 4;
      int gr = k + row;
      float4 v = (gr < n1) ? *reinterpret_cast<const float4*>(X + (size_t)gr * 64 + c4)
                           : float4{0, 0, 0, 0};
      *reinterpret_cast<float4*>(&Xl[row * 64 + c4]) = v;
    }
    {
      int q = t >> 2;
      int c16 = (t & 3) * 16;
#pragma unroll
      for (int jj = 0; jj < 4; ++jj) {
        int kk = c16 + jj * 4;
        int gk = k + kk;
        float4 v = (gk < n1) ? *reinterpret_cast<const float4*>(W + (size_t)q * N_U + gk)
                             : float4{0, 0, 0, 0};
        *reinterpret_cast<float4*>(&Wl[q * 65 + kk]) = v;
      }
    }
    __syncthreads();
#pragma unroll 2
    for (int kk = 0; kk < 64; kk += 4) {
      float4 w0 = *reinterpret_cast<const float4*>(&Wl[(q0 + 0) * 65 + kk]);
      float4 w1 = *reinterpret_cast<const float4*>(&Wl[(q0 + 1) * 65 + kk]);
      float4 w2 = *reinterpret_cast<const float4*>(&Wl[(q0 + 2) * 65 + kk]);
      float4 w3 = *reinterpret_cast<const float4*>(&Wl[(q0 + 3) * 65 + kk]);
      float4 x0 = *reinterpret_cast<const float4*>(&Xl[(kk + 0) * 64 + d0]);
      float4 x1 = *reinterpret_cast<const float4*>(&Xl[(kk + 1) * 64 + d0]);
      float4 x2 = *reinterpret_cast<const float4*>(&Xl[(kk + 2) * 64 + d0]);
      float4 x3 = *reinterpret_cast<const float4*>(&Xl[(kk + 3) * 64 + d0]);
#define FMA16(aj, wj)                                                                 \
  aj.x = fmaf(wj.x, x0.x, aj.x); aj.y = fmaf(wj.x, x0.y, aj.y);                       \
  aj.z = fmaf(wj.x, x0.z, aj.z); aj.w = fmaf(wj.x, x0.w, aj.w);                       \
  aj.x = fmaf(wj.y, x1.x, aj.x); aj.y = fmaf(wj.y, x1.y, aj.y);                       \
  aj.z = fmaf(wj.y, x1.z, aj.z); aj.w = fmaf(wj.y, x1.w, aj.w);                       \
  aj.x = fmaf(wj.z, x2.x, aj.x); aj.y = fmaf(wj.z, x2.y, aj.y);                       \
  aj.z = fmaf(wj.z, x2.z, aj.z); aj.w = fmaf(wj.z, x2.w, aj.w);                       \
  aj.x = fmaf(wj.w, x3.x, aj.x); aj.y = fmaf(wj.w, x3.y, aj.y);                       \
  aj.z = fmaf(wj.w, x3.z, aj.z); aj.w = fmaf(wj.w, x3.w, aj.w);
      FMA16(a0, w0)
      FMA16(a1, w1)
      FMA16(a2, w2)
      FMA16(a3, w3)
#undef FMA16
    }
    __syncthreads();
  }
  float* dst = Ppart + ((size_t)mat * G1_NBLK + blockIdx.x) * (Q * D);
  *reinterpret_cast<float4*>(dst + (q0 + 0) * 64 + d0) = a0;
  *reinterpret_cast<float4*>(dst + (q0 + 1) * 64 + d0) = a1;
  *reinterpret_cast<float4*>(dst + (q0 + 2) * 64 + d0) = a2;
  *reinterpret_cast<float4*>(dst + (q0 + 3) * 64 + d0) = a3;
}

// P[mat][q][d] = 3 * sum_blk Ppart[mat][blk][q][d]
__global__ void k_reduce(const float* __restrict__ Ppart, float* __restrict__ P) {
  int idx = blockIdx.x * 256 + threadIdx.x;  // 0..16383
  if (idx >= 2 * Q * D) return;
  int mat = idx >> 13;
  int qd = idx & (Q * D - 1);
  const float* src = Ppart + (size_t)mat * G1_NBLK * (Q * D) + qd;
  float s = 0.f;
#pragma unroll 4
  for (int b = 0; b < G1_NBLK; ++b) s += src[(size_t)b * (Q * D)];
  P[idx] = s * 3.f;
}

// ---------------- G2: out(N x 64) = M(N x 128) @ P(128 x 64) ----------------
__global__ void __launch_bounds__(256) k_g2(const float* __restrict__ u_mul_s,
                                            const float* __restrict__ v_mul_s,
                                            const float* __restrict__ P,
                                            float* __restrict__ svd_u,
                                            float* __restrict__ svd_i) {
  __shared__ float Pl[Q * D];  // 32 KB, [k][c] stride 64
  const int mat = blockIdx.y;
  const float* __restrict__ M  = mat ? v_mul_s : u_mul_s;  // (N_U, 128)
  const float* __restrict__ Pg = mat ? P : (P + Q * D);
  float* __restrict__ outp     = mat ? svd_i : svd_u;
  const int t = threadIdx.x;
#pragma unroll
  for (int i = 0; i < 8; ++i) {
    int idx = i * 256 + t;
    reinterpret_cast<float4*>(Pl)[idx] = reinterpret_cast<const float4*>(Pg)[idx];
  }
  __syncthreads();
  const int c0 = (t & 15) * 4;
  const int rbase = blockIdx.x * G2_ROWS + (t >> 4) * 4;
  const float4* mr0 = reinterpret_cast<const float4*>(M + (size_t)(rbase + 0 < N_U ? rbase + 0 : 0) * Q);
  const float4* mr1 = reinterpret_cast<const float4*>(M + (size_t)(rbase + 1 < N_U ? rbase + 1 : 0) * Q);
  const float4* mr2 = reinterpret_cast<const float4*>(M + (size_t)(rbase + 2 < N_U ? rbase + 2 : 0) * Q);
  const float4* mr3 = reinterpret_cast<const float4*>(M + (size_t)(rbase + 3 < N_U ? rbase + 3 : 0) * Q);
  float4 a0 = {0, 0, 0, 0}, a1 = {0, 0, 0, 0}, a2 = {0, 0, 0, 0}, a3 = {0, 0, 0, 0};
#pragma unroll 4
  for (int k4 = 0; k4 < Q / 4; ++k4) {
    float4 m0 = mr0[k4];
    float4 m1 = mr1[k4];
    float4 m2 = mr2[k4];
    float4 m3 = mr3[k4];
    float4 p0 = *reinterpret_cast<const float4*>(&Pl[(k4 * 4 + 0) * D + c0]);
    float4 p1 = *reinterpret_cast<const float4*>(&Pl[(k4 * 4 + 1) * D + c0]);
    float4 p2 = *reinterpret_cast<const float4*>(&Pl[(k4 * 4 + 2) * D + c0]);
    float4 p3 = *reinterpret_cast<const float4*>(&Pl[(k4 * 4 + 3) * D + c0]);
#define G2FMA(aj, mj)                                                                 \
  aj.x = fmaf(mj.x, p0.x, aj.x); aj.y = fmaf(mj.x, p0.y, aj.y);                       \
  aj.z = fmaf(mj.x, p0.z, aj.z); aj.w = fmaf(mj.x, p0.w, aj.w);                       \
  aj.x = fmaf(mj.y, p1.x, aj.x); aj.y = fmaf(mj.y, p1.y, aj.y);                       \
  aj.z = fmaf(mj.y, p1.z, aj.z); aj.w = fmaf(mj.y, p1.w, aj.w);                       \
  aj.x = fmaf(mj.z, p2.x, aj.x); aj.y = fmaf(mj.z, p2.y, aj.y);                       \
  aj.z = fmaf(mj.z, p2.z, aj.z); aj.w = fmaf(mj.z, p2.w, aj.w);                       \
  aj.x = fmaf(mj.w, p3.x, aj.x); aj.y = fmaf(mj.w, p3.y, aj.y);                       \
  aj.z = fmaf(mj.w, p3.z, aj.z); aj.w = fmaf(mj.w, p3.w, aj.w);
    G2FMA(a0, m0)
    G2FMA(a1, m1)
    G2FMA(a2, m2)
    G2FMA(a3, m3)
#undef G2FMA
  }
  if (rbase + 0 < N_U) *reinterpret_cast<float4*>(outp + (size_t)(rbase + 0) * D + c0) = a0;
  if (rbase + 1 < N_U) *reinterpret_cast<float4*>(outp + (size_t)(rbase + 1) * D + c0) = a1;
  if (rbase + 2 < N_U) *reinterpret_cast<float4*>(outp + (size_t)(rbase + 2) * D + c0) = a2;
  if (rbase + 3 < N_U) *reinterpret_cast<float4*>(outp + (size_t)(rbase + 3) * D + c0) = a3;
}

extern "C" void kernel_launch(void* const* d_in, const int* in_sizes, int n_in,
                              void* d_out, int out_size, void* d_ws, size_t ws_size,
                              hipStream_t stream) {
  const float* user_emb = (const float*)d_in[0];
  const float* item_emb = (const float*)d_in[1];
  const int*   adj_row  = (const int*)d_in[2];
  const int*   adj_col  = (const int*)d_in[3];
  const float* adj_vals = (const float*)d_in[4];
  const float* ut       = (const float*)d_in[5];
  const float* vt       = (const float*)d_in[6];
  const float* u_mul_s  = (const float*)d_in[7];
  const float* v_mul_s  = (const float*)d_in[8];
  float* out = (float*)d_out;

  char* ws = (char*)d_ws;
  size_t off = 0;
  auto alloc = [&](size_t bytes) -> void* {
    void* p = ws + off;
    off = (off + bytes + 255) & ~(size_t)255;
    return p;
  };
  unsigned short* eb0 = (unsigned short*)alloc((size_t)NTOT * D * 2);  // 25.6 MB
  unsigned short* eb1 = (unsigned short*)alloc((size_t)NTOT * D * 2);
  unsigned short* eb2 = (unsigned short*)alloc((size_t)NTOT * D * 2);
  int2*  ebuck  = (int2*)alloc((size_t)NNZ * 8);                  // 25.6 MB
  int2*  edges  = (int2*)alloc((size_t)NNZ * 8);                  // 25.6 MB
  int*   rowptr = (int*)alloc((size_t)(NTOT + 1) * 4);
  int*   part   = (int*)alloc((size_t)P_NBLK * NBUCK * 4);        // 611 KB
  int*   outb   = (int*)alloc((size_t)P_NBLK * NBUCK * 4);        // 611 KB
  int*   btot   = (int*)alloc((size_t)NBUCK * 4);
  int*   bbase  = (int*)alloc((size_t)(NBUCK + 1) * 4);
  float* P      = (float*)alloc(2 * Q * D * 4);                   // 64 KB
  float* Ppart  = (float*)alloc((size_t)2 * G1_NBLK * Q * D * 4); // 16.4 MB

  float* mean_u = out;                   // seg0
  float* svd_u  = out + (size_t)SEG;     // seg1
  float* mean_i = out + 2 * (size_t)SEG; // seg2
  float* svd_i  = out + 3 * (size_t)SEG; // seg3

  // CSR build (atomic-free multisplit) + fused input cvt
  k_pre<<<P_NBLK + CVT_BLKS, 512, 0, stream>>>(adj_row, part, user_emb, item_emb, eb0);
  k_bscanA<<<NBUCK, 64, 0, stream>>>(part, outb, btot);
  k_bscanB<<<1, 512, 0, stream>>>(btot, bbase);
  k_mscat<<<P_NBLK, 512, 0, stream>>>(adj_row, adj_col, adj_vals, outb, bbase, ebuck);
  k_rsort<<<NBUCK, 512, 0, stream>>>(bbase, ebuck, edges, rowptr);

  // SpMM: 2 rows/wave -> NTOT/2 waves -> NTOT*64/512 blocks
  const int spmmGrid = (NTOT * 64) / 512;
  k_spmm<0><<<spmmGrid, 256, 0, stream>>>(rowptr, edges, (const unsigned*)eb0,
                                          (unsigned*)eb1, nullptr, nullptr,
                                          nullptr, nullptr);
  k_spmm<0><<<spmmGrid, 256, 0, stream>>>(rowptr, edges, (const unsigned*)eb1,
                                          (unsigned*)eb2, nullptr, nullptr,
                                          nullptr, nullptr);
  // layer 3 fused with mean: reads e1,e2, writes f32 mean segments
  k_spmm<1><<<spmmGrid, 256, 0, stream>>>(rowptr, edges, (const unsigned*)eb2,
                                          nullptr, (const unsigned*)eb1,
                                          (const unsigned*)eb2, mean_u, mean_i);

  // P_u partials (y=0, from mean_u/ut), P_v partials (y=1, from mean_i/vt)
  k_g1<<<dim3(G1_NBLK, 2), 512, 0, stream>>>(ut, vt, mean_u, mean_i, Ppart);
  k_reduce<<<(2 * Q * D + 255) / 256, 256, 0, stream>>>(Ppart, P);

  // y=0: svd_u = u_mul_s @ P_v ; y=1: svd_i = v_mul_s @ P_u
  k_g2<<<dim3(G2_NBLK, 2), 256, 0, stream>>>(u_mul_s, v_mul_s, P, svd_u, svd_i);
}